// Round 10
// baseline (1417.449 us; speedup 1.0000x reference)
//
#include <hip/hip_runtime.h>
#include <hip/hip_bf16.h>
#include <math.h>

#define S_   1000
#define B_   4
#define D_   1024
#define H_   16
#define HD_  64
#define L_   4
#define FF_  4096
#define N_   (S_*B_)   /* 4000 token rows */

typedef __bf16 bf16x8 __attribute__((ext_vector_type(8)));
typedef float  f32x4  __attribute__((ext_vector_type(4)));
typedef __attribute__((address_space(3))) unsigned short lds_u16;

__device__ __forceinline__ unsigned short f2b(float f) {
    unsigned u = __builtin_bit_cast(unsigned, f);
    u = (u + 0x7FFFu + ((u >> 16) & 1u)) >> 16;   // RNE
    return (unsigned short)u;
}
__device__ __forceinline__ float b2f(unsigned short s) {
    unsigned u = (unsigned)s << 16;
    return __builtin_bit_cast(float, u);
}

__device__ __forceinline__ void gl16(const void* g, void* l) {
    __builtin_amdgcn_global_load_lds(
        (const __attribute__((address_space(1))) unsigned int*)g,
        (__attribute__((address_space(3))) unsigned int*)l, 16, 0, 0);
}

// inline-asm LDS read: invisible to compiler's mem-dep model, so it cannot
// auto-insert vmcnt(0) between global_load_lds and this read.
__device__ __forceinline__ bf16x8 ldsr(unsigned addr) {
    bf16x8 r;
    asm volatile("ds_read_b128 %0, %1" : "=v"(r) : "v"(addr));
    return r;
}

// ---------------- embedding lookup ----------------
__global__ void embed_kernel(const int* __restrict__ tokens,
                             const float* __restrict__ emb,
                             float* __restrict__ x) {
    int n = blockIdx.x;
    int tok = tokens[n];
    const float4* src = (const float4*)(emb + (size_t)tok * D_);
    float4* dst = (float4*)(x + (size_t)n * D_);
    dst[threadIdx.x] = src[threadIdx.x];
}

// ---------------- weight fp32->bf16 conversion (one layer, 12M elems) ----------------
__global__ __launch_bounds__(256)
void cvtw_kernel(const float* __restrict__ wq, const float* __restrict__ wk,
                 const float* __restrict__ wv, const float* __restrict__ wo,
                 const float* __restrict__ w1, const float* __restrict__ w2,
                 unsigned short* __restrict__ dst) {
    const size_t M1 = (size_t)D_ * D_;
    const size_t M4 = (size_t)FF_ * D_;
    size_t i = ((size_t)blockIdx.x * 256 + threadIdx.x) * 4;
    const float* src; size_t off;
    if      (i < M1)        { src = wq; off = i; }
    else if (i < 2*M1)      { src = wk; off = i - M1; }
    else if (i < 3*M1)      { src = wv; off = i - 2*M1; }
    else if (i < 4*M1)      { src = wo; off = i - 3*M1; }
    else if (i < 4*M1+M4)   { src = w1; off = i - 4*M1; }
    else                    { src = w2; off = i - 4*M1 - M4; }
    float4 v = *(const float4*)(src + off);
    ushort4 u;
    u.x = f2b(v.x); u.y = f2b(v.y); u.z = f2b(v.z); u.w = f2b(v.w);
    *(ushort4*)(dst + i) = u;
}

// ---------------- layernorm: fp32 in, bf16 out ----------------
__global__ __launch_bounds__(256)
void ln_kernel(const float* __restrict__ in,
               const float* __restrict__ g,
               const float* __restrict__ b,
               unsigned short* __restrict__ out) {
    int n = blockIdx.x;
    int tid = threadIdx.x;
    const float4* row = (const float4*)(in + (size_t)n * D_);
    float4 v = row[tid];
    float s  = v.x + v.y + v.z + v.w;
    float sq = v.x*v.x + v.y*v.y + v.z*v.z + v.w*v.w;
    #pragma unroll
    for (int off = 32; off; off >>= 1) {
        s  += __shfl_down(s, off);
        sq += __shfl_down(sq, off);
    }
    __shared__ float rs[4], rq[4];
    int wid = tid >> 6;
    if ((tid & 63) == 0) { rs[wid] = s; rq[wid] = sq; }
    __syncthreads();
    s  = rs[0] + rs[1] + rs[2] + rs[3];
    sq = rq[0] + rq[1] + rq[2] + rq[3];
    float mean = s * (1.0f / D_);
    float var  = sq * (1.0f / D_) - mean * mean;
    float rstd = rsqrtf(var + 1e-5f);
    float4 gg = ((const float4*)g)[tid];
    float4 bb = ((const float4*)b)[tid];
    ushort4 o;
    o.x = f2b((v.x - mean) * rstd * gg.x + bb.x);
    o.y = f2b((v.y - mean) * rstd * gg.y + bb.y);
    o.z = f2b((v.z - mean) * rstd * gg.z + bb.z);
    o.w = f2b((v.w - mean) * rstd * gg.w + bb.w);
    ((ushort4*)(out + (size_t)n * D_))[tid] = o;
}

// ---------------- 256x256 asm-ds_read 2-phase bf16 MFMA GEMM ----------------
// m248 2-phase config: 512 thr = 8 waves (2M x 4N), wave tile 128x64, BK=64,
// dbuf 128 KB LDS (1 blk/CU). Same discipline as agemm (asm ds_read, counted
// waits, setprio, both-sides XOR swizzle) but 4x MFMA work per barrier.
// MODE 0: QKV split — E=3072, o0/o1/o2 bf16 stride 1024, q scaled 0.125
// MODE 1: GELU — o0 bf16 stride FF_
template<int MODE>
__global__ __launch_bounds__(512, 1)
void bgemm_kernel(const unsigned short* __restrict__ A,
                  const unsigned short* __restrict__ W,
                  const float* __restrict__ bb0, const float* __restrict__ bb1,
                  const float* __restrict__ bb2,
                  unsigned short* __restrict__ o0, unsigned short* __restrict__ o1,
                  unsigned short* __restrict__ o2,
                  int M, int K) {
    __shared__ __align__(16) unsigned short As[2][256 * 64];
    __shared__ __align__(16) unsigned short Bs[2][256 * 64];
    int tid = threadIdx.x;
    int w = tid >> 6, lane = tid & 63;
    int wr = w >> 2, wc = w & 3;            // 2M x 4N waves
    int m0 = blockIdx.x * 256, e0 = blockIdx.y * 256;
    int l15 = lane & 15, l4 = lane >> 4, l7 = lane & 7;

    f32x4 acc[8][4] = {};

    auto stage = [&](int buf, int kt) {
        #pragma unroll
        for (int rep = 0; rep < 4; ++rep) {
            int slot = rep * 512 + tid;            // 0..2047
            int r = slot >> 3, c = slot & 7;
            int ar = m0 + r; if (ar > M - 1) ar = M - 1;
            gl16(A + (size_t)ar * K + kt + (c ^ (r & 7)) * 8, &As[buf][slot * 8]);
        }
        #pragma unroll
        for (int rep = 0; rep < 4; ++rep) {
            int slot = rep * 512 + tid;
            int r = slot >> 3, c = slot & 7;
            gl16(W + (size_t)(e0 + r) * K + kt + (c ^ (r & 7)) * 8, &Bs[buf][slot * 8]);
        }
    };

    int aoff[8], boff[4];
    #pragma unroll
    for (int i = 0; i < 8; ++i) aoff[i] = (wr * 128 + i * 16 + l15) * 128;
    #pragma unroll
    for (int j = 0; j < 4; ++j) boff[j] = (wc * 64 + j * 16 + l15) * 128;

    stage(0, 0);
    asm volatile("s_waitcnt vmcnt(0)" ::: "memory");
    __builtin_amdgcn_sched_barrier(0);
    __builtin_amdgcn_s_barrier();

    int nk = K >> 6;
    for (int t = 0; t < nk; ++t) {
        int cur = t & 1;
        if (t + 1 < nk) stage(cur ^ 1, (t + 1) << 6);
        __builtin_amdgcn_sched_barrier(0);          // stage issued first
        unsigned aB = (unsigned)(size_t)(lds_u16*)&As[cur][0];
        unsigned bB = (unsigned)(size_t)(lds_u16*)&Bs[cur][0];
        #pragma unroll
        for (int ks = 0; ks < 2; ++ks) {
            unsigned soff = (unsigned)((((ks * 4) + l4) ^ l7) * 16);
            bf16x8 av[8], bv[4];
            #pragma unroll
            for (int j = 0; j < 4; ++j) bv[j] = ldsr(bB + boff[j] + soff);
            #pragma unroll
            for (int i = 0; i < 8; ++i) av[i] = ldsr(aB + aoff[i] + soff);
            asm volatile("s_waitcnt lgkmcnt(0)" ::: "memory");
            __builtin_amdgcn_sched_barrier(0);      // rule #18 fence
            __builtin_amdgcn_s_setprio(1);
            #pragma unroll
            for (int i = 0; i < 8; ++i)
                #pragma unroll
                for (int j = 0; j < 4; ++j)
                    acc[i][j] = __builtin_amdgcn_mfma_f32_16x16x32_bf16(av[i], bv[j], acc[i][j], 0, 0, 0);
            __builtin_amdgcn_s_setprio(0);
        }
        asm volatile("s_waitcnt vmcnt(0)" ::: "memory");   // stage(t+1) landed
        __builtin_amdgcn_sched_barrier(0);
        __builtin_amdgcn_s_barrier();
    }

    // ---- epilogue (C/D: col=lane&15, row=(lane>>4)*4+reg) ----
    if (MODE == 0) {
        int sel = e0 >> 10;                 // 256-tile never crosses 1024 boundary
        int eobase = (e0 & 1023) + wc * 64;
        const float* bp = (sel == 0) ? bb0 : (sel == 1) ? bb1 : bb2;
        unsigned short* op = (sel == 0) ? o0 : (sel == 1) ? o1 : o2;
        float scale = (sel == 0) ? 0.125f : 1.0f;
        #pragma unroll
        for (int i = 0; i < 8; ++i) {
            int mrow = m0 + wr*128 + i*16 + l4*4;
            #pragma unroll
            for (int j = 0; j < 4; ++j) {
                int eo = eobase + j*16 + l15;
                float bval = bp[eo];
                #pragma unroll
                for (int r = 0; r < 4; ++r) {
                    int m = mrow + r;
                    if (m >= M) continue;
                    op[(size_t)m * 1024 + eo] = f2b((acc[i][j][r] + bval) * scale);
                }
            }
        }
    } else {
        #pragma unroll
        for (int i = 0; i < 8; ++i) {
            int mrow = m0 + wr*128 + i*16 + l4*4;
            #pragma unroll
            for (int j = 0; j < 4; ++j) {
                int e = e0 + wc*64 + j*16 + l15;
                float bval = bb0[e];
                #pragma unroll
                for (int r = 0; r < 4; ++r) {
                    int m = mrow + r;
                    if (m >= M) continue;
                    float val = acc[i][j][r] + bval;
                    val = 0.5f * val * (1.0f + erff(val * 0.70710678118654752f));
                    o0[(size_t)m * FF_ + e] = f2b(val);
                }
            }
        }
    }
}

// ---------------- 128x128 asm-ds_read 2-phase bf16 MFMA GEMM ----------------
// MODE 1: GELU — o0v bf16 stride FF_;  MODE 2: +residual — o0v fp32 stride 1024
template<int MODE>
__global__ __launch_bounds__(256, 2)
void agemm_kernel(const unsigned short* __restrict__ A,
                  const unsigned short* __restrict__ W,
                  const float* __restrict__ bb0,
                  const float* __restrict__ res,
                  void* __restrict__ o0v,
                  int M, int K) {
    __shared__ __align__(16) unsigned short As[2][128 * 64];
    __shared__ __align__(16) unsigned short Bs[2][128 * 64];
    int tid = threadIdx.x;
    int w = tid >> 6, lane = tid & 63;
    int wr = w >> 1, wc = w & 1;
    int m0 = blockIdx.x * 128, e0 = blockIdx.y * 128;
    int l15 = lane & 15, l4 = lane >> 4, l7 = lane & 7;

    f32x4 acc[4][4] = {};

    auto stage = [&](int buf, int kt) {
        #pragma unroll
        for (int rep = 0; rep < 4; ++rep) {
            int slot = rep * 256 + tid;
            int r = slot >> 3, c = slot & 7;
            int ar = m0 + r; if (ar > M - 1) ar = M - 1;
            gl16(A + (size_t)ar * K + kt + (c ^ (r & 7)) * 8, &As[buf][slot * 8]);
        }
        #pragma unroll
        for (int rep = 0; rep < 4; ++rep) {
            int slot = rep * 256 + tid;
            int r = slot >> 3, c = slot & 7;
            gl16(W + (size_t)(e0 + r) * K + kt + (c ^ (r & 7)) * 8, &Bs[buf][slot * 8]);
        }
    };

    int aoff[4], boff[4];
    #pragma unroll
    for (int i = 0; i < 4; ++i) {
        aoff[i] = (wr * 64 + i * 16 + l15) * 128;
        boff[i] = (wc * 64 + i * 16 + l15) * 128;
    }

    stage(0, 0);
    asm volatile("s_waitcnt vmcnt(0)" ::: "memory");
    __builtin_amdgcn_sched_barrier(0);
    __builtin_amdgcn_s_barrier();

    int nk = K >> 6;
    for (int t = 0; t < nk; ++t) {
        int cur = t & 1;
        if (t + 1 < nk) stage(cur ^ 1, (t + 1) << 6);
        __builtin_amdgcn_sched_barrier(0);
        unsigned aB = (unsigned)(size_t)(lds_u16*)&As[cur][0];
        unsigned bB = (unsigned)(size_t)(lds_u16*)&Bs[cur][0];
        #pragma unroll
        for (int ks = 0; ks < 2; ++ks) {
            unsigned soff = (unsigned)((((ks * 4) + l4) ^ l7) * 16);
            bf16x8 av[4], bv[4];
            #pragma unroll
            for (int i = 0; i < 4; ++i) av[i] = ldsr(aB + aoff[i] + soff);
            #pragma unroll
            for (int j = 0; j < 4; ++j) bv[j] = ldsr(bB + boff[j] + soff);
            asm volatile("s_waitcnt lgkmcnt(0)" ::: "memory");
            __builtin_amdgcn_sched_barrier(0);
            __builtin_amdgcn_s_setprio(1);
            #pragma unroll
            for (int i = 0; i < 4; ++i)
                #pragma unroll
                for (int j = 0; j < 4; ++j)
                    acc[i][j] = __builtin_amdgcn_mfma_f32_16x16x32_bf16(av[i], bv[j], acc[i][j], 0, 0, 0);
            __builtin_amdgcn_s_setprio(0);
        }
        asm volatile("s_waitcnt vmcnt(0)" ::: "memory");
        __builtin_amdgcn_sched_barrier(0);
        __builtin_amdgcn_s_barrier();
    }

    if (MODE == 1) {
        unsigned short* op = (unsigned short*)o0v;
        #pragma unroll
        for (int i = 0; i < 4; ++i) {
            int mrow = m0 + wr*64 + i*16 + l4*4;
            #pragma unroll
            for (int j = 0; j < 4; ++j) {
                int e = e0 + wc*64 + j*16 + l15;
                float bval = bb0[e];
                #pragma unroll
                for (int r = 0; r < 4; ++r) {
                    int m = mrow + r;
                    if (m >= M) continue;
                    float val = acc[i][j][r] + bval;
                    val = 0.5f * val * (1.0f + erff(val * 0.70710678118654752f));
                    op[(size_t)m * FF_ + e] = f2b(val);
                }
            }
        }
    } else {
        float* op = (float*)o0v;
        #pragma unroll
        for (int i = 0; i < 4; ++i) {
            int mrow = m0 + wr*64 + i*16 + l4*4;
            #pragma unroll
            for (int j = 0; j < 4; ++j) {
                int e = e0 + wc*64 + j*16 + l15;
                float bval = bb0[e];
                #pragma unroll
                for (int r = 0; r < 4; ++r) {
                    int m = mrow + r;
                    if (m >= M) continue;
                    op[(size_t)m * 1024 + e] = acc[i][j][r] + bval + res[(size_t)m * 1024 + e];
                }
            }
        }
    }
}

// ---------------- fp32 tiled GEMM (final 64-col projection only) ----------------
__global__ __launch_bounds__(256)
void gemm_kernel(const float* __restrict__ A, const float* __restrict__ W,
                 const float* __restrict__ bias, float* __restrict__ C,
                 int M, int K, int E) {
    __shared__ float As[32][64];
    __shared__ float Ws[32][64];
    int tid = threadIdx.x;
    int m0 = blockIdx.x * 64, e0 = blockIdx.y * 64;
    int tx = tid & 15, ty = tid >> 4;
    int lrow = tid >> 2;
    int lkc  = (tid & 3) * 8;
    float acc[4][4] = {};
    const float* Arow = A + (size_t)(m0 + lrow) * K + lkc;
    const float* Wrow = W + (size_t)(e0 + lrow) * K + lkc;
    bool aval = (m0 + lrow) < M;

    for (int k0 = 0; k0 < K; k0 += 32) {
        float4 a0 = make_float4(0.f,0.f,0.f,0.f), a1 = a0;
        if (aval) {
            a0 = *(const float4*)(Arow + k0);
            a1 = *(const float4*)(Arow + k0 + 4);
        }
        float4 w0 = *(const float4*)(Wrow + k0);
        float4 w1 = *(const float4*)(Wrow + k0 + 4);
        As[lkc+0][lrow] = a0.x; As[lkc+1][lrow] = a0.y;
        As[lkc+2][lrow] = a0.z; As[lkc+3][lrow] = a0.w;
        As[lkc+4][lrow] = a1.x; As[lkc+5][lrow] = a1.y;
        As[lkc+6][lrow] = a1.z; As[lkc+7][lrow] = a1.w;
        Ws[lkc+0][lrow] = w0.x; Ws[lkc+1][lrow] = w0.y;
        Ws[lkc+2][lrow] = w0.z; Ws[lkc+3][lrow] = w0.w;
        Ws[lkc+4][lrow] = w1.x; Ws[lkc+5][lrow] = w1.y;
        Ws[lkc+6][lrow] = w1.z; Ws[lkc+7][lrow] = w1.w;
        __syncthreads();
        #pragma unroll
        for (int kk = 0; kk < 32; ++kk) {
            float4 a = *(const float4*)(&As[kk][ty*4]);
            float4 ww = *(const float4*)(&Ws[kk][tx*4]);
            acc[0][0] += a.x*ww.x; acc[0][1] += a.x*ww.y; acc[0][2] += a.x*ww.z; acc[0][3] += a.x*ww.w;
            acc[1][0] += a.y*ww.x; acc[1][1] += a.y*ww.y; acc[1][2] += a.y*ww.z; acc[1][3] += a.y*ww.w;
            acc[2][0] += a.z*ww.x; acc[2][1] += a.z*ww.y; acc[2][2] += a.z*ww.z; acc[2][3] += a.z*ww.w;
            acc[3][0] += a.w*ww.x; acc[3][1] += a.w*ww.y; acc[3][2] += a.w*ww.z; acc[3][3] += a.w*ww.w;
        }
        __syncthreads();
    }
    #pragma unroll
    for (int i = 0; i < 4; ++i) {
        int m = m0 + ty*4 + i;
        if (m >= M) continue;
        #pragma unroll
        for (int j = 0; j < 4; ++j) {
            int e = e0 + tx*4 + j;
            C[(size_t)m * E + e] = acc[i][j] + bias[e];
        }
    }
}

// ---------------- RoPE in place on bf16 [N, H*HD] ----------------
__global__ void ropeb_kernel(unsigned short* __restrict__ x) {
    int idx = blockIdx.x * 256 + threadIdx.x;
    if (idx >= N_ * H_ * 32) return;
    int j = idx & 31;
    int h = (idx >> 5) & (H_ - 1);
    int n = idx >> 9;
    int s = n >> 2;
    float inv = __expf(-(float)j * 0.2878231366242557f);  // ln(10000)/32
    float ang = (float)s * inv;
    float sn, cs;
    __sincosf(ang, &sn, &cs);
    unsigned short* p = x + (size_t)n * D_ + h * HD_ + j;
    float a = b2f(p[0]), c = b2f(p[32]);
    p[0]  = f2b(a * cs - c * sn);
    p[32] = f2b(c * cs + a * sn);
}

// ---------------- V transpose: [s][b][h*64+d] bf16 -> [bh][d][1024] bf16 ----------------
__global__ __launch_bounds__(256)
void vtr_kernel(const unsigned short* __restrict__ vin,
                unsigned short* __restrict__ vout) {
    __shared__ unsigned short T[64][65];
    int tt = blockIdx.x;
    int bh = blockIdx.y;
    int b = bh >> 4, h = bh & 15;
    int tid = threadIdx.x;
    #pragma unroll
    for (int rep = 0; rep < 2; ++rep) {
        int slot = rep * 256 + tid;
        int r = slot >> 3, ch = slot & 7;
        int t = tt * 64 + r;
        unsigned short e[8] = {0,0,0,0,0,0,0,0};
        if (t < S_) {
            const unsigned short* src = vin + ((size_t)t * B_ + b) * D_ + h * HD_ + ch * 8;
            *(ushort4*)&e[0] = *(const ushort4*)(src);
            *(ushort4*)&e[4] = *(const ushort4*)(src + 4);
        }
        #pragma unroll
        for (int u = 0; u < 8; ++u) T[r][ch*8+u] = e[u];
    }
    __syncthreads();
    #pragma unroll
    for (int rep = 0; rep < 2; ++rep) {
        int slot = rep * 256 + tid;
        int d = slot >> 3, ch = slot & 7;
        unsigned short e[8];
        #pragma unroll
        for (int u = 0; u < 8; ++u) e[u] = T[ch*8+u][d];
        unsigned short* dst = vout + ((size_t)bh * 64 + d) * 1024 + tt * 64 + ch * 8;
        *(ushort4*)(dst)     = *(ushort4*)&e[0];
        *(ushort4*)(dst + 4) = *(ushort4*)&e[4];
    }
}

// ---------------- bf16 MFMA flash attention ----------------
__global__ __launch_bounds__(256)
void mattn_kernel(const unsigned short* __restrict__ qg,
                  const unsigned short* __restrict__ kg,
                  const unsigned short* __restrict__ vt,
                  unsigned short* __restrict__ o) {
    __shared__ __align__(16) unsigned short Ks[64 * 64];
    __shared__ __align__(16) unsigned short Vs[64 * 64];
    __shared__ __align__(16) unsigned short Ps[4][16 * 64];

    int bid = blockIdx.x;
    int qt = bid & 15;
    int bh = bid >> 4;
    int b = bh >> 4, h = bh & 15;
    int tid = threadIdx.x;
    int w = tid >> 6, lane = tid & 63;
    int l15 = lane & 15, l4 = lane >> 4, l7 = lane & 7;
    int q0 = qt * 64 + w * 16;

    int srow = lane >> 3;
    int schunk = ((lane & 7) ^ srow) * 8;

    bf16x8 qfr[2];
    {
        int qr = q0 + l15; if (qr > S_ - 1) qr = S_ - 1;
        const unsigned short* qrow = qg + ((size_t)qr * B_ + b) * D_ + h * HD_;
        qfr[0] = *(const bf16x8*)(qrow + l4 * 8);
        qfr[1] = *(const bf16x8*)(qrow + 32 + l4 * 8);
    }

    f32x4 accO[4] = {};
    float mreg[4] = {-1e30f, -1e30f, -1e30f, -1e30f};
    float lreg[4] = {0.f, 0.f, 0.f, 0.f};

    for (int t0 = 0; t0 < 1024; t0 += 64) {
        __syncthreads();
        #pragma unroll
        for (int c = 0; c < 2; ++c) {
            int r0 = w * 16 + c * 8;
            int tr = t0 + r0 + srow; if (tr > S_ - 1) tr = S_ - 1;
            gl16(kg + ((size_t)tr * B_ + b) * D_ + h * HD_ + schunk, &Ks[r0 * 64]);
            gl16(vt + ((size_t)bh * 64 + r0 + srow) * 1024 + t0 + schunk, &Vs[r0 * 64]);
        }
        __syncthreads();

        f32x4 s[4] = {};
        #pragma unroll
        for (int ks = 0; ks < 2; ++ks) {
            int cc = ks * 4 + l4;
            int slot = (cc ^ l7) * 16;
            #pragma unroll
            for (int j = 0; j < 4; ++j) {
                bf16x8 kf = *(const bf16x8*)((const char*)Ks + (j*16 + l15) * 128 + slot);
                s[j] = __builtin_amdgcn_mfma_f32_16x16x32_bf16(qfr[ks], kf, s[j], 0, 0, 0);
            }
        }
        #pragma unroll
        for (int j = 0; j < 4; ++j) {
            int t = t0 + j * 16 + l15;
            if (t >= S_) { s[j][0] = -1e30f; s[j][1] = -1e30f; s[j][2] = -1e30f; s[j][3] = -1e30f; }
        }
        float rm[4], sc[4], rsum[4];
        #pragma unroll
        for (int r = 0; r < 4; ++r)
            rm[r] = fmaxf(fmaxf(s[0][r], s[1][r]), fmaxf(s[2][r], s[3][r]));
        #pragma unroll
        for (int mk = 1; mk <= 8; mk <<= 1) {
            #pragma unroll
            for (int r = 0; r < 4; ++r) rm[r] = fmaxf(rm[r], __shfl_xor(rm[r], mk));
        }
        #pragma unroll
        for (int r = 0; r < 4; ++r) {
            float mn = fmaxf(mreg[r], rm[r]);
            sc[r] = __expf(mreg[r] - mn);
            mreg[r] = mn;
            rsum[r] = 0.f;
        }
        #pragma unroll
        for (int j = 0; j < 4; ++j) {
            int inb = (j * 16 + l15) * 2;
            #pragma unroll
            for (int r = 0; r < 4; ++r) {
                float p = __expf(s[j][r] - mreg[r]);
                rsum[r] += p;
                int row = l4 * 4 + r;
                *(unsigned short*)((char*)&Ps[w][0] + row * 128 +
                    ((((inb >> 4) ^ (row & 7)) << 4)) + (inb & 15)) = f2b(p);
            }
        }
        #pragma unroll
        for (int mk = 1; mk <= 8; mk <<= 1) {
            #pragma unroll
            for (int r = 0; r < 4; ++r) rsum[r] += __shfl_xor(rsum[r], mk);
        }
        #pragma unroll
        for (int r = 0; r < 4; ++r) lreg[r] = lreg[r] * sc[r] + rsum[r];
        #pragma unroll
        for (int j = 0; j < 4; ++j) {
            accO[j][0] *= sc[0]; accO[j][1] *= sc[1];
            accO[j][2] *= sc[2]; accO[j][3] *= sc[3];
        }
        #pragma unroll
        for (int ks = 0; ks < 2; ++ks) {
            int cc = ks * 4 + l4;
            int slot = (cc ^ l7) * 16;
            bf16x8 pf = *(const bf16x8*)((const char*)&Ps[w][0] + l15 * 128 + slot);
            #pragma unroll
            for (int j = 0; j < 4; ++j) {
                bf16x8 vf = *(const bf16x8*)((const char*)Vs + (j*16 + l15) * 128 + slot);
                accO[j] = __builtin_amdgcn_mfma_f32_16x16x32_bf16(pf, vf, accO[j], 0, 0, 0);
            }
        }
    }
    #pragma unroll
    for (int r = 0; r < 4; ++r) {
        int q = q0 + l4 * 4 + r;
        if (q >= S_) continue;
        float inv = 1.0f / lreg[r];
        unsigned short* orow = o + ((size_t)q * B_ + b) * D_ + h * HD_;
        #pragma unroll
        for (int j = 0; j < 4; ++j)
            orow[j * 16 + l15] = f2b(accO[j][r] * inv);
    }
}

extern "C" void kernel_launch(void* const* d_in, const int* in_sizes, int n_in,
                              void* d_out, int out_size, void* d_ws, size_t ws_size,
                              hipStream_t stream) {
    const int*   tokens = (const int*)  d_in[0];
    const float* Wemb   = (const float*)d_in[1];
    const float* Wq     = (const float*)d_in[2];
    const float* bq     = (const float*)d_in[3];
    const float* Wk     = (const float*)d_in[4];
    const float* bk     = (const float*)d_in[5];
    const float* Wv     = (const float*)d_in[6];
    const float* bv     = (const float*)d_in[7];
    const float* Wo     = (const float*)d_in[8];
    const float* bo     = (const float*)d_in[9];
    const float* ln1g   = (const float*)d_in[10];
    const float* ln1b   = (const float*)d_in[11];
    const float* ln2g   = (const float*)d_in[12];
    const float* ln2b   = (const float*)d_in[13];
    const float* W1     = (const float*)d_in[14];
    const float* b1     = (const float*)d_in[15];
    const float* W2     = (const float*)d_in[16];
    const float* b2     = (const float*)d_in[17];
    const float* Wout   = (const float*)d_in[18];
    const float* bout   = (const float*)d_in[19];
    float* out = (float*)d_out;

    const size_t ND = (size_t)N_ * D_;
    const size_t NF = (size_t)N_ * FF_;
    const size_t M1 = (size_t)D_ * D_;
    const size_t M4 = (size_t)FF_ * D_;
    const size_t VT = (size_t)64 * 64 * 1024;

    float* x  = (float*)d_ws;
    unsigned short* hb = (unsigned short*)(x + ND);
    unsigned short* qb = hb + ND;
    unsigned short* kb = qb + ND;
    unsigned short* vb = kb + ND;
    unsigned short* ob = vb + ND;
    unsigned short* vt = ob + ND;
    unsigned short* f1 = vt + VT;
    unsigned short* wb = f1 + NF;           // 12M bf16 per-layer weights

    dim3 blk(256);
    embed_kernel<<<N_, blk, 0, stream>>>(tokens, Wemb, x);

    dim3 gQKV(16, 12);   // 256² tiles: M=4000->16, E=3072->12
    dim3 gW1(16, 16);    // E=4096->16
    dim3 gE(32, 8);      // 128² tiles for E=1024 gemms
    dim3 gCv(12288);
    int rth = N_ * H_ * 32;
    dim3 gR((rth + 255) / 256);
    dim3 gVt(16, 64);
    dim3 gAt(16 * 64);
    dim3 gOut((N_ + 63) / 64, 1);

    for (int l = 0; l < L_; ++l) {
        cvtw_kernel<<<gCv, blk, 0, stream>>>(Wq + l*M1, Wk + l*M1, Wv + l*M1,
                                             Wo + l*M1, W1 + l*M4, W2 + l*M4, wb);
        ln_kernel<<<N_, blk, 0, stream>>>(x, ln1g + l*D_, ln1b + l*D_, hb);
        bgemm_kernel<0><<<gQKV, dim3(512), 0, stream>>>(hb, wb,
            bq + l*D_, bk + l*D_, bv + l*D_, qb, kb, vb, N_, D_);
        ropeb_kernel<<<gR, blk, 0, stream>>>(qb);
        ropeb_kernel<<<gR, blk, 0, stream>>>(kb);
        vtr_kernel<<<gVt, blk, 0, stream>>>(vb, vt);
        mattn_kernel<<<gAt, blk, 0, stream>>>(qb, kb, vt, ob);
        agemm_kernel<2><<<gE, blk, 0, stream>>>(ob, wb + 3*M1,
            bo + l*D_, x, x, N_, D_);
        ln_kernel<<<N_, blk, 0, stream>>>(x, ln2g + l*D_, ln2b + l*D_, hb);
        bgemm_kernel<1><<<gW1, dim3(512), 0, stream>>>(hb, wb + 4*M1,
            b1 + l*FF_, nullptr, nullptr, f1, nullptr, nullptr, N_, D_);
        agemm_kernel<2><<<gE, blk, 0, stream>>>(f1, wb + 4*M1 + M4,
            b2 + l*D_, x, x, N_, FF_);
    }
    gemm_kernel<<<gOut, blk, 0, stream>>>(x, Wout, bout, out, N_, D_, 64);
}

// Round 11
// 1332.664 us; speedup vs baseline: 1.0636x; 1.0636x over previous
//
#include <hip/hip_runtime.h>
#include <hip/hip_bf16.h>
#include <math.h>

#define S_   1000
#define B_   4
#define D_   1024
#define H_   16
#define HD_  64
#define L_   4
#define FF_  4096
#define N_   (S_*B_)   /* 4000 token rows */

typedef __bf16 bf16x8 __attribute__((ext_vector_type(8)));
typedef float  f32x4  __attribute__((ext_vector_type(4)));
typedef __attribute__((address_space(3))) unsigned short lds_u16;

__device__ __forceinline__ unsigned short f2b(float f) {
    unsigned u = __builtin_bit_cast(unsigned, f);
    u = (u + 0x7FFFu + ((u >> 16) & 1u)) >> 16;   // RNE
    return (unsigned short)u;
}
__device__ __forceinline__ float b2f(unsigned short s) {
    unsigned u = (unsigned)s << 16;
    return __builtin_bit_cast(float, u);
}

__device__ __forceinline__ void gl16(const void* g, void* l) {
    __builtin_amdgcn_global_load_lds(
        (const __attribute__((address_space(1))) unsigned int*)g,
        (__attribute__((address_space(3))) unsigned int*)l, 16, 0, 0);
}

// inline-asm LDS read: invisible to compiler's mem-dep model, so it cannot
// auto-insert vmcnt(0) between global_load_lds and this read.
__device__ __forceinline__ bf16x8 ldsr(unsigned addr) {
    bf16x8 r;
    asm volatile("ds_read_b128 %0, %1" : "=v"(r) : "v"(addr));
    return r;
}

// ---------------- embedding lookup ----------------
__global__ void embed_kernel(const int* __restrict__ tokens,
                             const float* __restrict__ emb,
                             float* __restrict__ x) {
    int n = blockIdx.x;
    int tok = tokens[n];
    const float4* src = (const float4*)(emb + (size_t)tok * D_);
    float4* dst = (float4*)(x + (size_t)n * D_);
    dst[threadIdx.x] = src[threadIdx.x];
}

// ---------------- weight fp32->bf16 conversion (one layer, 12M elems) ----------------
__global__ __launch_bounds__(256)
void cvtw_kernel(const float* __restrict__ wq, const float* __restrict__ wk,
                 const float* __restrict__ wv, const float* __restrict__ wo,
                 const float* __restrict__ w1, const float* __restrict__ w2,
                 unsigned short* __restrict__ dst) {
    const size_t M1 = (size_t)D_ * D_;
    const size_t M4 = (size_t)FF_ * D_;
    size_t i = ((size_t)blockIdx.x * 256 + threadIdx.x) * 4;
    const float* src; size_t off;
    if      (i < M1)        { src = wq; off = i; }
    else if (i < 2*M1)      { src = wk; off = i - M1; }
    else if (i < 3*M1)      { src = wv; off = i - 2*M1; }
    else if (i < 4*M1)      { src = wo; off = i - 3*M1; }
    else if (i < 4*M1+M4)   { src = w1; off = i - 4*M1; }
    else                    { src = w2; off = i - 4*M1 - M4; }
    float4 v = *(const float4*)(src + off);
    ushort4 u;
    u.x = f2b(v.x); u.y = f2b(v.y); u.z = f2b(v.z); u.w = f2b(v.w);
    *(ushort4*)(dst + i) = u;
}

// ---------------- layernorm: fp32 in, bf16 out ----------------
__global__ __launch_bounds__(256)
void ln_kernel(const float* __restrict__ in,
               const float* __restrict__ g,
               const float* __restrict__ b,
               unsigned short* __restrict__ out) {
    int n = blockIdx.x;
    int tid = threadIdx.x;
    const float4* row = (const float4*)(in + (size_t)n * D_);
    float4 v = row[tid];
    float s  = v.x + v.y + v.z + v.w;
    float sq = v.x*v.x + v.y*v.y + v.z*v.z + v.w*v.w;
    #pragma unroll
    for (int off = 32; off; off >>= 1) {
        s  += __shfl_down(s, off);
        sq += __shfl_down(sq, off);
    }
    __shared__ float rs[4], rq[4];
    int wid = tid >> 6;
    if ((tid & 63) == 0) { rs[wid] = s; rq[wid] = sq; }
    __syncthreads();
    s  = rs[0] + rs[1] + rs[2] + rs[3];
    sq = rq[0] + rq[1] + rq[2] + rq[3];
    float mean = s * (1.0f / D_);
    float var  = sq * (1.0f / D_) - mean * mean;
    float rstd = rsqrtf(var + 1e-5f);
    float4 gg = ((const float4*)g)[tid];
    float4 bb = ((const float4*)b)[tid];
    ushort4 o;
    o.x = f2b((v.x - mean) * rstd * gg.x + bb.x);
    o.y = f2b((v.y - mean) * rstd * gg.y + bb.y);
    o.z = f2b((v.z - mean) * rstd * gg.z + bb.z);
    o.w = f2b((v.w - mean) * rstd * gg.w + bb.w);
    ((ushort4*)(out + (size_t)n * D_))[tid] = o;
}

// ---------------- 256x128 ring-3 depth-2 asm-ds_read bf16 MFMA GEMM ----------------
// Round-7 geometry (512 thr = 8 waves 4x2, wave tile 64x64, BK=64, 3-buffer
// ring 144 KB LDS, prefetch depth 2) + round-9 discipline (asm ds_read so the
// compiler cannot inject a vmcnt(0) drain; counted vmcnt(12/6/0); lgkm fence;
// setprio). Stage = 6 gl16/thread. Per step: stage(t+2) -> vmcnt(12) [tile t
// landed; t+1,t+2 in flight] -> barrier -> 2x{8 ldsr + lgkm(0) + 16 MFMA} ->
// barrier [slot (t+2)%3's prior readers finished at step t-1's end barrier].
// MODE 0: QKV split — E=3072, o0/o1/o2 bf16 stride 1024, q scaled 0.125
// MODE 1: GELU — o0 bf16 stride FF_
template<int MODE>
__global__ __launch_bounds__(512, 1)
void cgemm_kernel(const unsigned short* __restrict__ A,
                  const unsigned short* __restrict__ W,
                  const float* __restrict__ bb0, const float* __restrict__ bb1,
                  const float* __restrict__ bb2,
                  unsigned short* __restrict__ o0, unsigned short* __restrict__ o1,
                  unsigned short* __restrict__ o2,
                  int M, int K) {
    __shared__ __align__(16) unsigned short Ab[3][256 * 64];   // 96 KB
    __shared__ __align__(16) unsigned short Bb[3][128 * 64];   // 48 KB
    int tid = threadIdx.x;
    int w = tid >> 6, lane = tid & 63;
    int wr = w >> 1, wc = w & 1;            // 4M x 2N waves, 64x64 each
    int m0 = blockIdx.x * 256, e0 = blockIdx.y * 128;
    int l15 = lane & 15, l4 = lane >> 4, l7 = lane & 7;

    f32x4 acc[4][4] = {};

    auto stage = [&](int rs, int kt) {
        #pragma unroll
        for (int rep = 0; rep < 4; ++rep) {            // A: 256 rows
            int slot = rep * 512 + tid;                // 0..2047
            int r = slot >> 3, c = slot & 7;
            int ar = m0 + r; if (ar > M - 1) ar = M - 1;
            gl16(A + (size_t)ar * K + kt + (c ^ (r & 7)) * 8, &Ab[rs][slot * 8]);
        }
        #pragma unroll
        for (int rep = 0; rep < 2; ++rep) {            // B: 128 rows
            int slot = rep * 512 + tid;
            int r = slot >> 3, c = slot & 7;
            gl16(W + (size_t)(e0 + r) * K + kt + (c ^ (r & 7)) * 8, &Bb[rs][slot * 8]);
        }
    };

    int aoff[4], boff[4];
    #pragma unroll
    for (int i = 0; i < 4; ++i) {
        aoff[i] = (wr * 64 + i * 16 + l15) * 128;
        boff[i] = (wc * 64 + i * 16 + l15) * 128;
    }

    int nk = K >> 6;
    stage(0, 0);
    if (nk > 1) stage(1, 64);
    for (int t = 0; t < nk; ++t) {
        int rs = t % 3;
        if (t + 2 < nk) {
            stage((t + 2) % 3, (t + 2) << 6);
            asm volatile("s_waitcnt vmcnt(12)" ::: "memory");   // tile t landed
        } else if (t + 1 < nk) {
            asm volatile("s_waitcnt vmcnt(6)" ::: "memory");
        } else {
            asm volatile("s_waitcnt vmcnt(0)" ::: "memory");
        }
        __builtin_amdgcn_sched_barrier(0);
        __builtin_amdgcn_s_barrier();
        unsigned aB = (unsigned)(size_t)(lds_u16*)&Ab[rs][0];
        unsigned bB = (unsigned)(size_t)(lds_u16*)&Bb[rs][0];
        #pragma unroll
        for (int ks = 0; ks < 2; ++ks) {
            unsigned soff = (unsigned)((((ks * 4) + l4) ^ l7) * 16);
            bf16x8 av[4], bv[4];
            #pragma unroll
            for (int i = 0; i < 4; ++i) av[i] = ldsr(aB + aoff[i] + soff);
            #pragma unroll
            for (int j = 0; j < 4; ++j) bv[j] = ldsr(bB + boff[j] + soff);
            asm volatile("s_waitcnt lgkmcnt(0)" ::: "memory");
            __builtin_amdgcn_sched_barrier(0);          // rule #18 fence
            __builtin_amdgcn_s_setprio(1);
            #pragma unroll
            for (int i = 0; i < 4; ++i)
                #pragma unroll
                for (int j = 0; j < 4; ++j)
                    acc[i][j] = __builtin_amdgcn_mfma_f32_16x16x32_bf16(av[i], bv[j], acc[i][j], 0, 0, 0);
            __builtin_amdgcn_s_setprio(0);
        }
        __builtin_amdgcn_sched_barrier(0);
        __builtin_amdgcn_s_barrier();       // reads drained (lgkm above); slot reusable
    }

    // ---- epilogue (C/D: col=lane&15, row=(lane>>4)*4+reg) ----
    if (MODE == 0) {
        int sel = e0 >> 10;                 // 128-tile never crosses 1024 boundary
        int eobase = (e0 & 1023) + wc * 64;
        const float* bp = (sel == 0) ? bb0 : (sel == 1) ? bb1 : bb2;
        unsigned short* op = (sel == 0) ? o0 : (sel == 1) ? o1 : o2;
        float scale = (sel == 0) ? 0.125f : 1.0f;
        #pragma unroll
        for (int i = 0; i < 4; ++i) {
            int mrow = m0 + wr*64 + i*16 + l4*4;
            #pragma unroll
            for (int j = 0; j < 4; ++j) {
                int eo = eobase + j*16 + l15;
                float bval = bp[eo];
                #pragma unroll
                for (int r = 0; r < 4; ++r) {
                    int m = mrow + r;
                    if (m >= M) continue;
                    op[(size_t)m * 1024 + eo] = f2b((acc[i][j][r] + bval) * scale);
                }
            }
        }
    } else {
        #pragma unroll
        for (int i = 0; i < 4; ++i) {
            int mrow = m0 + wr*64 + i*16 + l4*4;
            #pragma unroll
            for (int j = 0; j < 4; ++j) {
                int e = e0 + wc*64 + j*16 + l15;
                float bval = bb0[e];
                #pragma unroll
                for (int r = 0; r < 4; ++r) {
                    int m = mrow + r;
                    if (m >= M) continue;
                    float val = acc[i][j][r] + bval;
                    val = 0.5f * val * (1.0f + erff(val * 0.70710678118654752f));
                    o0[(size_t)m * FF_ + e] = f2b(val);
                }
            }
        }
    }
}

// ---------------- 128x128 asm-ds_read 2-phase bf16 MFMA GEMM ----------------
// MODE 1: GELU — o0v bf16 stride FF_;  MODE 2: +residual — o0v fp32 stride 1024
template<int MODE>
__global__ __launch_bounds__(256, 2)
void agemm_kernel(const unsigned short* __restrict__ A,
                  const unsigned short* __restrict__ W,
                  const float* __restrict__ bb0,
                  const float* __restrict__ res,
                  void* __restrict__ o0v,
                  int M, int K) {
    __shared__ __align__(16) unsigned short As[2][128 * 64];
    __shared__ __align__(16) unsigned short Bs[2][128 * 64];
    int tid = threadIdx.x;
    int w = tid >> 6, lane = tid & 63;
    int wr = w >> 1, wc = w & 1;
    int m0 = blockIdx.x * 128, e0 = blockIdx.y * 128;
    int l15 = lane & 15, l4 = lane >> 4, l7 = lane & 7;

    f32x4 acc[4][4] = {};

    auto stage = [&](int buf, int kt) {
        #pragma unroll
        for (int rep = 0; rep < 4; ++rep) {
            int slot = rep * 256 + tid;
            int r = slot >> 3, c = slot & 7;
            int ar = m0 + r; if (ar > M - 1) ar = M - 1;
            gl16(A + (size_t)ar * K + kt + (c ^ (r & 7)) * 8, &As[buf][slot * 8]);
        }
        #pragma unroll
        for (int rep = 0; rep < 4; ++rep) {
            int slot = rep * 256 + tid;
            int r = slot >> 3, c = slot & 7;
            gl16(W + (size_t)(e0 + r) * K + kt + (c ^ (r & 7)) * 8, &Bs[buf][slot * 8]);
        }
    };

    int aoff[4], boff[4];
    #pragma unroll
    for (int i = 0; i < 4; ++i) {
        aoff[i] = (wr * 64 + i * 16 + l15) * 128;
        boff[i] = (wc * 64 + i * 16 + l15) * 128;
    }

    stage(0, 0);
    asm volatile("s_waitcnt vmcnt(0)" ::: "memory");
    __builtin_amdgcn_sched_barrier(0);
    __builtin_amdgcn_s_barrier();

    int nk = K >> 6;
    for (int t = 0; t < nk; ++t) {
        int cur = t & 1;
        if (t + 1 < nk) stage(cur ^ 1, (t + 1) << 6);
        __builtin_amdgcn_sched_barrier(0);
        unsigned aB = (unsigned)(size_t)(lds_u16*)&As[cur][0];
        unsigned bB = (unsigned)(size_t)(lds_u16*)&Bs[cur][0];
        #pragma unroll
        for (int ks = 0; ks < 2; ++ks) {
            unsigned soff = (unsigned)((((ks * 4) + l4) ^ l7) * 16);
            bf16x8 av[4], bv[4];
            #pragma unroll
            for (int i = 0; i < 4; ++i) av[i] = ldsr(aB + aoff[i] + soff);
            #pragma unroll
            for (int j = 0; j < 4; ++j) bv[j] = ldsr(bB + boff[j] + soff);
            asm volatile("s_waitcnt lgkmcnt(0)" ::: "memory");
            __builtin_amdgcn_sched_barrier(0);
            __builtin_amdgcn_s_setprio(1);
            #pragma unroll
            for (int i = 0; i < 4; ++i)
                #pragma unroll
                for (int j = 0; j < 4; ++j)
                    acc[i][j] = __builtin_amdgcn_mfma_f32_16x16x32_bf16(av[i], bv[j], acc[i][j], 0, 0, 0);
            __builtin_amdgcn_s_setprio(0);
        }
        asm volatile("s_waitcnt vmcnt(0)" ::: "memory");
        __builtin_amdgcn_sched_barrier(0);
        __builtin_amdgcn_s_barrier();
    }

    if (MODE == 1) {
        unsigned short* op = (unsigned short*)o0v;
        #pragma unroll
        for (int i = 0; i < 4; ++i) {
            int mrow = m0 + wr*64 + i*16 + l4*4;
            #pragma unroll
            for (int j = 0; j < 4; ++j) {
                int e = e0 + wc*64 + j*16 + l15;
                float bval = bb0[e];
                #pragma unroll
                for (int r = 0; r < 4; ++r) {
                    int m = mrow + r;
                    if (m >= M) continue;
                    float val = acc[i][j][r] + bval;
                    val = 0.5f * val * (1.0f + erff(val * 0.70710678118654752f));
                    op[(size_t)m * FF_ + e] = f2b(val);
                }
            }
        }
    } else {
        float* op = (float*)o0v;
        #pragma unroll
        for (int i = 0; i < 4; ++i) {
            int mrow = m0 + wr*64 + i*16 + l4*4;
            #pragma unroll
            for (int j = 0; j < 4; ++j) {
                int e = e0 + wc*64 + j*16 + l15;
                float bval = bb0[e];
                #pragma unroll
                for (int r = 0; r < 4; ++r) {
                    int m = mrow + r;
                    if (m >= M) continue;
                    op[(size_t)m * 1024 + e] = acc[i][j][r] + bval + res[(size_t)m * 1024 + e];
                }
            }
        }
    }
}

// ---------------- fp32 tiled GEMM (final 64-col projection only) ----------------
__global__ __launch_bounds__(256)
void gemm_kernel(const float* __restrict__ A, const float* __restrict__ W,
                 const float* __restrict__ bias, float* __restrict__ C,
                 int M, int K, int E) {
    __shared__ float As[32][64];
    __shared__ float Ws[32][64];
    int tid = threadIdx.x;
    int m0 = blockIdx.x * 64, e0 = blockIdx.y * 64;
    int tx = tid & 15, ty = tid >> 4;
    int lrow = tid >> 2;
    int lkc  = (tid & 3) * 8;
    float acc[4][4] = {};
    const float* Arow = A + (size_t)(m0 + lrow) * K + lkc;
    const float* Wrow = W + (size_t)(e0 + lrow) * K + lkc;
    bool aval = (m0 + lrow) < M;

    for (int k0 = 0; k0 < K; k0 += 32) {
        float4 a0 = make_float4(0.f,0.f,0.f,0.f), a1 = a0;
        if (aval) {
            a0 = *(const float4*)(Arow + k0);
            a1 = *(const float4*)(Arow + k0 + 4);
        }
        float4 w0 = *(const float4*)(Wrow + k0);
        float4 w1 = *(const float4*)(Wrow + k0 + 4);
        As[lkc+0][lrow] = a0.x; As[lkc+1][lrow] = a0.y;
        As[lkc+2][lrow] = a0.z; As[lkc+3][lrow] = a0.w;
        As[lkc+4][lrow] = a1.x; As[lkc+5][lrow] = a1.y;
        As[lkc+6][lrow] = a1.z; As[lkc+7][lrow] = a1.w;
        Ws[lkc+0][lrow] = w0.x; Ws[lkc+1][lrow] = w0.y;
        Ws[lkc+2][lrow] = w0.z; Ws[lkc+3][lrow] = w0.w;
        Ws[lkc+4][lrow] = w1.x; Ws[lkc+5][lrow] = w1.y;
        Ws[lkc+6][lrow] = w1.z; Ws[lkc+7][lrow] = w1.w;
        __syncthreads();
        #pragma unroll
        for (int kk = 0; kk < 32; ++kk) {
            float4 a = *(const float4*)(&As[kk][ty*4]);
            float4 ww = *(const float4*)(&Ws[kk][tx*4]);
            acc[0][0] += a.x*ww.x; acc[0][1] += a.x*ww.y; acc[0][2] += a.x*ww.z; acc[0][3] += a.x*ww.w;
            acc[1][0] += a.y*ww.x; acc[1][1] += a.y*ww.y; acc[1][2] += a.y*ww.z; acc[1][3] += a.y*ww.w;
            acc[2][0] += a.z*ww.x; acc[2][1] += a.z*ww.y; acc[2][2] += a.z*ww.z; acc[2][3] += a.z*ww.w;
            acc[3][0] += a.w*ww.x; acc[3][1] += a.w*ww.y; acc[3][2] += a.w*ww.z; acc[3][3] += a.w*ww.w;
        }
        __syncthreads();
    }
    #pragma unroll
    for (int i = 0; i < 4; ++i) {
        int m = m0 + ty*4 + i;
        if (m >= M) continue;
        #pragma unroll
        for (int j = 0; j < 4; ++j) {
            int e = e0 + tx*4 + j;
            C[(size_t)m * E + e] = acc[i][j] + bias[e];
        }
    }
}

// ---------------- RoPE in place on bf16 [N, H*HD] ----------------
__global__ void ropeb_kernel(unsigned short* __restrict__ x) {
    int idx = blockIdx.x * 256 + threadIdx.x;
    if (idx >= N_ * H_ * 32) return;
    int j = idx & 31;
    int h = (idx >> 5) & (H_ - 1);
    int n = idx >> 9;
    int s = n >> 2;
    float inv = __expf(-(float)j * 0.2878231366242557f);  // ln(10000)/32
    float ang = (float)s * inv;
    float sn, cs;
    __sincosf(ang, &sn, &cs);
    unsigned short* p = x + (size_t)n * D_ + h * HD_ + j;
    float a = b2f(p[0]), c = b2f(p[32]);
    p[0]  = f2b(a * cs - c * sn);
    p[32] = f2b(c * cs + a * sn);
}

// ---------------- V transpose: [s][b][h*64+d] bf16 -> [bh][d][1024] bf16 ----------------
__global__ __launch_bounds__(256)
void vtr_kernel(const unsigned short* __restrict__ vin,
                unsigned short* __restrict__ vout) {
    __shared__ unsigned short T[64][65];
    int tt = blockIdx.x;
    int bh = blockIdx.y;
    int b = bh >> 4, h = bh & 15;
    int tid = threadIdx.x;
    #pragma unroll
    for (int rep = 0; rep < 2; ++rep) {
        int slot = rep * 256 + tid;
        int r = slot >> 3, ch = slot & 7;
        int t = tt * 64 + r;
        unsigned short e[8] = {0,0,0,0,0,0,0,0};
        if (t < S_) {
            const unsigned short* src = vin + ((size_t)t * B_ + b) * D_ + h * HD_ + ch * 8;
            *(ushort4*)&e[0] = *(const ushort4*)(src);
            *(ushort4*)&e[4] = *(const ushort4*)(src + 4);
        }
        #pragma unroll
        for (int u = 0; u < 8; ++u) T[r][ch*8+u] = e[u];
    }
    __syncthreads();
    #pragma unroll
    for (int rep = 0; rep < 2; ++rep) {
        int slot = rep * 256 + tid;
        int d = slot >> 3, ch = slot & 7;
        unsigned short e[8];
        #pragma unroll
        for (int u = 0; u < 8; ++u) e[u] = T[ch*8+u][d];
        unsigned short* dst = vout + ((size_t)bh * 64 + d) * 1024 + tt * 64 + ch * 8;
        *(ushort4*)(dst)     = *(ushort4*)&e[0];
        *(ushort4*)(dst + 4) = *(ushort4*)&e[4];
    }
}

// ---------------- bf16 MFMA flash attention ----------------
__global__ __launch_bounds__(256)
void mattn_kernel(const unsigned short* __restrict__ qg,
                  const unsigned short* __restrict__ kg,
                  const unsigned short* __restrict__ vt,
                  unsigned short* __restrict__ o) {
    __shared__ __align__(16) unsigned short Ks[64 * 64];
    __shared__ __align__(16) unsigned short Vs[64 * 64];
    __shared__ __align__(16) unsigned short Ps[4][16 * 64];

    int bid = blockIdx.x;
    int qt = bid & 15;
    int bh = bid >> 4;
    int b = bh >> 4, h = bh & 15;
    int tid = threadIdx.x;
    int w = tid >> 6, lane = tid & 63;
    int l15 = lane & 15, l4 = lane >> 4, l7 = lane & 7;
    int q0 = qt * 64 + w * 16;

    int srow = lane >> 3;
    int schunk = ((lane & 7) ^ srow) * 8;

    bf16x8 qfr[2];
    {
        int qr = q0 + l15; if (qr > S_ - 1) qr = S_ - 1;
        const unsigned short* qrow = qg + ((size_t)qr * B_ + b) * D_ + h * HD_;
        qfr[0] = *(const bf16x8*)(qrow + l4 * 8);
        qfr[1] = *(const bf16x8*)(qrow + 32 + l4 * 8);
    }

    f32x4 accO[4] = {};
    float mreg[4] = {-1e30f, -1e30f, -1e30f, -1e30f};
    float lreg[4] = {0.f, 0.f, 0.f, 0.f};

    for (int t0 = 0; t0 < 1024; t0 += 64) {
        __syncthreads();
        #pragma unroll
        for (int c = 0; c < 2; ++c) {
            int r0 = w * 16 + c * 8;
            int tr = t0 + r0 + srow; if (tr > S_ - 1) tr = S_ - 1;
            gl16(kg + ((size_t)tr * B_ + b) * D_ + h * HD_ + schunk, &Ks[r0 * 64]);
            gl16(vt + ((size_t)bh * 64 + r0 + srow) * 1024 + t0 + schunk, &Vs[r0 * 64]);
        }
        __syncthreads();

        f32x4 s[4] = {};
        #pragma unroll
        for (int ks = 0; ks < 2; ++ks) {
            int cc = ks * 4 + l4;
            int slot = (cc ^ l7) * 16;
            #pragma unroll
            for (int j = 0; j < 4; ++j) {
                bf16x8 kf = *(const bf16x8*)((const char*)Ks + (j*16 + l15) * 128 + slot);
                s[j] = __builtin_amdgcn_mfma_f32_16x16x32_bf16(qfr[ks], kf, s[j], 0, 0, 0);
            }
        }
        #pragma unroll
        for (int j = 0; j < 4; ++j) {
            int t = t0 + j * 16 + l15;
            if (t >= S_) { s[j][0] = -1e30f; s[j][1] = -1e30f; s[j][2] = -1e30f; s[j][3] = -1e30f; }
        }
        float rm[4], sc[4], rsum[4];
        #pragma unroll
        for (int r = 0; r < 4; ++r)
            rm[r] = fmaxf(fmaxf(s[0][r], s[1][r]), fmaxf(s[2][r], s[3][r]));
        #pragma unroll
        for (int mk = 1; mk <= 8; mk <<= 1) {
            #pragma unroll
            for (int r = 0; r < 4; ++r) rm[r] = fmaxf(rm[r], __shfl_xor(rm[r], mk));
        }
        #pragma unroll
        for (int r = 0; r < 4; ++r) {
            float mn = fmaxf(mreg[r], rm[r]);
            sc[r] = __expf(mreg[r] - mn);
            mreg[r] = mn;
            rsum[r] = 0.f;
        }
        #pragma unroll
        for (int j = 0; j < 4; ++j) {
            int inb = (j * 16 + l15) * 2;
            #pragma unroll
            for (int r = 0; r < 4; ++r) {
                float p = __expf(s[j][r] - mreg[r]);
                rsum[r] += p;
                int row = l4 * 4 + r;
                *(unsigned short*)((char*)&Ps[w][0] + row * 128 +
                    ((((inb >> 4) ^ (row & 7)) << 4)) + (inb & 15)) = f2b(p);
            }
        }
        #pragma unroll
        for (int mk = 1; mk <= 8; mk <<= 1) {
            #pragma unroll
            for (int r = 0; r < 4; ++r) rsum[r] += __shfl_xor(rsum[r], mk);
        }
        #pragma unroll
        for (int r = 0; r < 4; ++r) lreg[r] = lreg[r] * sc[r] + rsum[r];
        #pragma unroll
        for (int j = 0; j < 4; ++j) {
            accO[j][0] *= sc[0]; accO[j][1] *= sc[1];
            accO[j][2] *= sc[2]; accO[j][3] *= sc[3];
        }
        #pragma unroll
        for (int ks = 0; ks < 2; ++ks) {
            int cc = ks * 4 + l4;
            int slot = (cc ^ l7) * 16;
            bf16x8 pf = *(const bf16x8*)((const char*)&Ps[w][0] + l15 * 128 + slot);
            #pragma unroll
            for (int j = 0; j < 4; ++j) {
                bf16x8 vf = *(const bf16x8*)((const char*)Vs + (j*16 + l15) * 128 + slot);
                accO[j] = __builtin_amdgcn_mfma_f32_16x16x32_bf16(pf, vf, accO[j], 0, 0, 0);
            }
        }
    }
    #pragma unroll
    for (int r = 0; r < 4; ++r) {
        int q = q0 + l4 * 4 + r;
        if (q >= S_) continue;
        float inv = 1.0f / lreg[r];
        unsigned short* orow = o + ((size_t)q * B_ + b) * D_ + h * HD_;
        #pragma unroll
        for (int j = 0; j < 4; ++j)
            orow[j * 16 + l15] = f2b(accO[j][r] * inv);
    }
}

extern "C" void kernel_launch(void* const* d_in, const int* in_sizes, int n_in,
                              void* d_out, int out_size, void* d_ws, size_t ws_size,
                              hipStream_t stream) {
    const int*   tokens = (const int*)  d_in[0];
    const float* Wemb   = (const float*)d_in[1];
    const float* Wq     = (const float*)d_in[2];
    const float* bq     = (const float*)d_in[3];
    const float* Wk     = (const float*)d_in[4];
    const float* bk     = (const float*)d_in[5];
    const float* Wv     = (const float*)d_in[6];
    const float* bv     = (const float*)d_in[7];
    const float* Wo     = (const float*)d_in[8];
    const float* bo     = (const float*)d_in[9];
    const float* ln1g   = (const float*)d_in[10];
    const float* ln1b   = (const float*)d_in[11];
    const float* ln2g   = (const float*)d_in[12];
    const float* ln2b   = (const float*)d_in[13];
    const float* W1     = (const float*)d_in[14];
    const float* b1     = (const float*)d_in[15];
    const float* W2     = (const float*)d_in[16];
    const float* b2     = (const float*)d_in[17];
    const float* Wout   = (const float*)d_in[18];
    const float* bout   = (const float*)d_in[19];
    float* out = (float*)d_out;

    const size_t ND = (size_t)N_ * D_;
    const size_t NF = (size_t)N_ * FF_;
    const size_t M1 = (size_t)D_ * D_;
    const size_t M4 = (size_t)FF_ * D_;
    const size_t VT = (size_t)64 * 64 * 1024;

    float* x  = (float*)d_ws;
    unsigned short* hb = (unsigned short*)(x + ND);
    unsigned short* qb = hb + ND;
    unsigned short* kb = qb + ND;
    unsigned short* vb = kb + ND;
    unsigned short* ob = vb + ND;
    unsigned short* vt = ob + ND;
    unsigned short* f1 = vt + VT;
    unsigned short* wb = f1 + NF;           // 12M bf16 per-layer weights

    dim3 blk(256);
    embed_kernel<<<N_, blk, 0, stream>>>(tokens, Wemb, x);

    dim3 gQKV(16, 24);   // 256x128 tiles: M=4000->16, E=3072->24
    dim3 gW1(16, 32);    // E=4096->32
    dim3 gE(32, 8);      // 128² tiles for E=1024 gemms
    dim3 gCv(12288);
    int rth = N_ * H_ * 32;
    dim3 gR((rth + 255) / 256);
    dim3 gVt(16, 64);
    dim3 gAt(16 * 64);
    dim3 gOut((N_ + 63) / 64, 1);

    for (int l = 0; l < L_; ++l) {
        cvtw_kernel<<<gCv, blk, 0, stream>>>(Wq + l*M1, Wk + l*M1, Wv + l*M1,
                                             Wo + l*M1, W1 + l*M4, W2 + l*M4, wb);
        ln_kernel<<<N_, blk, 0, stream>>>(x, ln1g + l*D_, ln1b + l*D_, hb);
        cgemm_kernel<0><<<gQKV, dim3(512), 0, stream>>>(hb, wb,
            bq + l*D_, bk + l*D_, bv + l*D_, qb, kb, vb, N_, D_);
        ropeb_kernel<<<gR, blk, 0, stream>>>(qb);
        ropeb_kernel<<<gR, blk, 0, stream>>>(kb);
        vtr_kernel<<<gVt, blk, 0, stream>>>(vb, vt);
        mattn_kernel<<<gAt, blk, 0, stream>>>(qb, kb, vt, ob);
        agemm_kernel<2><<<gE, blk, 0, stream>>>(ob, wb + 3*M1,
            bo + l*D_, x, x, N_, D_);
        ln_kernel<<<N_, blk, 0, stream>>>(x, ln2g + l*D_, ln2b + l*D_, hb);
        cgemm_kernel<1><<<gW1, dim3(512), 0, stream>>>(hb, wb + 4*M1,
            b1 + l*FF_, nullptr, nullptr, f1, nullptr, nullptr, N_, D_);
        agemm_kernel<2><<<gE, blk, 0, stream>>>(f1, wb + 4*M1 + M4,
            b2 + l*D_, x, x, N_, FF_);
    }
    gemm_kernel<<<gOut, blk, 0, stream>>>(x, Wout, bout, out, N_, D_, 64);
}

// Round 12
// 1188.566 us; speedup vs baseline: 1.1926x; 1.1212x over previous
//
#include <hip/hip_runtime.h>
#include <hip/hip_bf16.h>
#include <math.h>

#define S_   1000
#define B_   4
#define D_   1024
#define H_   16
#define HD_  64
#define L_   4
#define FF_  4096
#define N_   (S_*B_)   /* 4000 token rows */

typedef __bf16 bf16x8 __attribute__((ext_vector_type(8)));
typedef float  f32x4  __attribute__((ext_vector_type(4)));
typedef __attribute__((address_space(3))) unsigned short lds_u16;

__device__ __forceinline__ unsigned short f2b(float f) {
    unsigned u = __builtin_bit_cast(unsigned, f);
    u = (u + 0x7FFFu + ((u >> 16) & 1u)) >> 16;   // RNE
    return (unsigned short)u;
}
__device__ __forceinline__ float b2f(unsigned short s) {
    unsigned u = (unsigned)s << 16;
    return __builtin_bit_cast(float, u);
}

__device__ __forceinline__ void gl16(const void* g, void* l) {
    __builtin_amdgcn_global_load_lds(
        (const __attribute__((address_space(1))) unsigned int*)g,
        (__attribute__((address_space(3))) unsigned int*)l, 16, 0, 0);
}

// inline-asm LDS read: invisible to compiler's mem-dep model, so it cannot
// auto-insert vmcnt(0) between global_load_lds and this read.
__device__ __forceinline__ bf16x8 ldsr(unsigned addr) {
    bf16x8 r;
    asm volatile("ds_read_b128 %0, %1" : "=v"(r) : "v"(addr));
    return r;
}

// ---------------- embedding lookup ----------------
__global__ void embed_kernel(const int* __restrict__ tokens,
                             const float* __restrict__ emb,
                             float* __restrict__ x) {
    int n = blockIdx.x;
    int tok = tokens[n];
    const float4* src = (const float4*)(emb + (size_t)tok * D_);
    float4* dst = (float4*)(x + (size_t)n * D_);
    dst[threadIdx.x] = src[threadIdx.x];
}

// ---------------- weight fp32->bf16 conversion (one layer, 12M elems) ----------------
__global__ __launch_bounds__(256)
void cvtw_kernel(const float* __restrict__ wq, const float* __restrict__ wk,
                 const float* __restrict__ wv, const float* __restrict__ wo,
                 const float* __restrict__ w1, const float* __restrict__ w2,
                 unsigned short* __restrict__ dst) {
    const size_t M1 = (size_t)D_ * D_;
    const size_t M4 = (size_t)FF_ * D_;
    size_t i = ((size_t)blockIdx.x * 256 + threadIdx.x) * 4;
    const float* src; size_t off;
    if      (i < M1)        { src = wq; off = i; }
    else if (i < 2*M1)      { src = wk; off = i - M1; }
    else if (i < 3*M1)      { src = wv; off = i - 2*M1; }
    else if (i < 4*M1)      { src = wo; off = i - 3*M1; }
    else if (i < 4*M1+M4)   { src = w1; off = i - 4*M1; }
    else                    { src = w2; off = i - 4*M1 - M4; }
    float4 v = *(const float4*)(src + off);
    ushort4 u;
    u.x = f2b(v.x); u.y = f2b(v.y); u.z = f2b(v.z); u.w = f2b(v.w);
    *(ushort4*)(dst + i) = u;
}

// ---------------- layernorm: fp32 in, bf16 out ----------------
__global__ __launch_bounds__(256)
void ln_kernel(const float* __restrict__ in,
               const float* __restrict__ g,
               const float* __restrict__ b,
               unsigned short* __restrict__ out) {
    int n = blockIdx.x;
    int tid = threadIdx.x;
    const float4* row = (const float4*)(in + (size_t)n * D_);
    float4 v = row[tid];
    float s  = v.x + v.y + v.z + v.w;
    float sq = v.x*v.x + v.y*v.y + v.z*v.z + v.w*v.w;
    #pragma unroll
    for (int off = 32; off; off >>= 1) {
        s  += __shfl_down(s, off);
        sq += __shfl_down(sq, off);
    }
    __shared__ float rs[4], rq[4];
    int wid = tid >> 6;
    if ((tid & 63) == 0) { rs[wid] = s; rq[wid] = sq; }
    __syncthreads();
    s  = rs[0] + rs[1] + rs[2] + rs[3];
    sq = rq[0] + rq[1] + rq[2] + rq[3];
    float mean = s * (1.0f / D_);
    float var  = sq * (1.0f / D_) - mean * mean;
    float rstd = rsqrtf(var + 1e-5f);
    float4 gg = ((const float4*)g)[tid];
    float4 bb = ((const float4*)b)[tid];
    ushort4 o;
    o.x = f2b((v.x - mean) * rstd * gg.x + bb.x);
    o.y = f2b((v.y - mean) * rstd * gg.y + bb.y);
    o.z = f2b((v.z - mean) * rstd * gg.z + bb.z);
    o.w = f2b((v.w - mean) * rstd * gg.w + bb.w);
    ((ushort4*)(out + (size_t)n * D_))[tid] = o;
}

// ---------------- 128x128 asm-ds_read 2-phase bf16 MFMA GEMM (round-9 proven) ----------------
// MODE 0: QKV split — E=3072, o0/o1/o2 bf16 stride 1024, q scaled 0.125
// MODE 1: GELU — o0 bf16 stride FF_
template<int MODE>
__global__ __launch_bounds__(256, 2)
void agemm_kernel(const unsigned short* __restrict__ A,
                  const unsigned short* __restrict__ W,
                  const float* __restrict__ bb0, const float* __restrict__ bb1,
                  const float* __restrict__ bb2,
                  unsigned short* __restrict__ o0, unsigned short* __restrict__ o1,
                  unsigned short* __restrict__ o2,
                  int M, int K) {
    __shared__ __align__(16) unsigned short As[2][128 * 64];
    __shared__ __align__(16) unsigned short Bs[2][128 * 64];
    int tid = threadIdx.x;
    int w = tid >> 6, lane = tid & 63;
    int wr = w >> 1, wc = w & 1;
    int m0 = blockIdx.x * 128, e0 = blockIdx.y * 128;
    int l15 = lane & 15, l4 = lane >> 4, l7 = lane & 7;

    f32x4 acc[4][4] = {};

    auto stage = [&](int buf, int kt) {
        #pragma unroll
        for (int rep = 0; rep < 4; ++rep) {
            int slot = rep * 256 + tid;
            int r = slot >> 3, c = slot & 7;
            int ar = m0 + r; if (ar > M - 1) ar = M - 1;
            gl16(A + (size_t)ar * K + kt + (c ^ (r & 7)) * 8, &As[buf][slot * 8]);
        }
        #pragma unroll
        for (int rep = 0; rep < 4; ++rep) {
            int slot = rep * 256 + tid;
            int r = slot >> 3, c = slot & 7;
            gl16(W + (size_t)(e0 + r) * K + kt + (c ^ (r & 7)) * 8, &Bs[buf][slot * 8]);
        }
    };

    int aoff[4], boff[4];
    #pragma unroll
    for (int i = 0; i < 4; ++i) {
        aoff[i] = (wr * 64 + i * 16 + l15) * 128;
        boff[i] = (wc * 64 + i * 16 + l15) * 128;
    }

    stage(0, 0);
    asm volatile("s_waitcnt vmcnt(0)" ::: "memory");
    __builtin_amdgcn_sched_barrier(0);
    __builtin_amdgcn_s_barrier();

    int nk = K >> 6;
    for (int t = 0; t < nk; ++t) {
        int cur = t & 1;
        if (t + 1 < nk) stage(cur ^ 1, (t + 1) << 6);
        __builtin_amdgcn_sched_barrier(0);
        unsigned aB = (unsigned)(size_t)(lds_u16*)&As[cur][0];
        unsigned bB = (unsigned)(size_t)(lds_u16*)&Bs[cur][0];
        #pragma unroll
        for (int ks = 0; ks < 2; ++ks) {
            unsigned soff = (unsigned)((((ks * 4) + l4) ^ l7) * 16);
            bf16x8 av[4], bv[4];
            #pragma unroll
            for (int i = 0; i < 4; ++i) av[i] = ldsr(aB + aoff[i] + soff);
            #pragma unroll
            for (int j = 0; j < 4; ++j) bv[j] = ldsr(bB + boff[j] + soff);
            asm volatile("s_waitcnt lgkmcnt(0)" ::: "memory");
            __builtin_amdgcn_sched_barrier(0);
            __builtin_amdgcn_s_setprio(1);
            #pragma unroll
            for (int i = 0; i < 4; ++i)
                #pragma unroll
                for (int j = 0; j < 4; ++j)
                    acc[i][j] = __builtin_amdgcn_mfma_f32_16x16x32_bf16(av[i], bv[j], acc[i][j], 0, 0, 0);
            __builtin_amdgcn_s_setprio(0);
        }
        asm volatile("s_waitcnt vmcnt(0)" ::: "memory");
        __builtin_amdgcn_sched_barrier(0);
        __builtin_amdgcn_s_barrier();
    }

    if (MODE == 0) {
        int sel = e0 >> 10;
        int eobase = (e0 & 1023) + wc * 64;
        const float* bp = (sel == 0) ? bb0 : (sel == 1) ? bb1 : bb2;
        unsigned short* op = (sel == 0) ? o0 : (sel == 1) ? o1 : o2;
        float scale = (sel == 0) ? 0.125f : 1.0f;
        #pragma unroll
        for (int i = 0; i < 4; ++i) {
            int mrow = m0 + wr*64 + i*16 + l4*4;
            #pragma unroll
            for (int j = 0; j < 4; ++j) {
                int eo = eobase + j*16 + l15;
                float bval = bp[eo];
                #pragma unroll
                for (int r = 0; r < 4; ++r) {
                    int m = mrow + r;
                    if (m >= M) continue;
                    op[(size_t)m * 1024 + eo] = f2b((acc[i][j][r] + bval) * scale);
                }
            }
        }
    } else {
        #pragma unroll
        for (int i = 0; i < 4; ++i) {
            int mrow = m0 + wr*64 + i*16 + l4*4;
            #pragma unroll
            for (int j = 0; j < 4; ++j) {
                int e = e0 + wc*64 + j*16 + l15;
                float bval = bb0[e];
                #pragma unroll
                for (int r = 0; r < 4; ++r) {
                    int m = mrow + r;
                    if (m >= M) continue;
                    float val = acc[i][j][r] + bval;
                    val = 0.5f * val * (1.0f + erff(val * 0.70710678118654752f));
                    o0[(size_t)m * FF_ + e] = f2b(val);
                }
            }
        }
    }
}

// ---------------- 128x64 asm-ds_read 2-phase GEMM for E=1024 (+residual) ----------------
// BN=64 halves per-block work vs agemm: grid 32x16 = 512 blocks (2/CU avg),
// LDS 48 KB dbuf -> 3 blocks/CU resident. Cross-block TLP hides the stage
// stall (the mechanism behind m102's N=4096 vs N=2048 gap).
// 4 waves 2x2, wave tile 64x32, acc[4][2]. Out fp32 stride 1024, res added.
__global__ __launch_bounds__(256, 2)
void dgemm_kernel(const unsigned short* __restrict__ A,
                  const unsigned short* __restrict__ W,
                  const float* __restrict__ bias,
                  const float* __restrict__ res,
                  float* __restrict__ out,
                  int M, int K) {
    __shared__ __align__(16) unsigned short As[2][128 * 64];   // 32 KB
    __shared__ __align__(16) unsigned short Bs[2][64 * 64];    // 16 KB
    int tid = threadIdx.x;
    int w = tid >> 6, lane = tid & 63;
    int wr = w >> 1, wc = w & 1;
    int m0 = blockIdx.x * 128, e0 = blockIdx.y * 64;
    int l15 = lane & 15, l4 = lane >> 4, l7 = lane & 7;

    f32x4 acc[4][2] = {};

    auto stage = [&](int buf, int kt) {
        #pragma unroll
        for (int rep = 0; rep < 4; ++rep) {
            int slot = rep * 256 + tid;            // 0..1023, A: 128 rows
            int r = slot >> 3, c = slot & 7;
            int ar = m0 + r; if (ar > M - 1) ar = M - 1;
            gl16(A + (size_t)ar * K + kt + (c ^ (r & 7)) * 8, &As[buf][slot * 8]);
        }
        #pragma unroll
        for (int rep = 0; rep < 2; ++rep) {
            int slot = rep * 256 + tid;            // 0..511, B: 64 rows
            int r = slot >> 3, c = slot & 7;
            gl16(W + (size_t)(e0 + r) * K + kt + (c ^ (r & 7)) * 8, &Bs[buf][slot * 8]);
        }
    };

    int aoff[4], boff[2];
    #pragma unroll
    for (int i = 0; i < 4; ++i) aoff[i] = (wr * 64 + i * 16 + l15) * 128;
    #pragma unroll
    for (int j = 0; j < 2; ++j) boff[j] = (wc * 32 + j * 16 + l15) * 128;

    stage(0, 0);
    asm volatile("s_waitcnt vmcnt(0)" ::: "memory");
    __builtin_amdgcn_sched_barrier(0);
    __builtin_amdgcn_s_barrier();

    int nk = K >> 6;
    for (int t = 0; t < nk; ++t) {
        int cur = t & 1;
        if (t + 1 < nk) stage(cur ^ 1, (t + 1) << 6);
        __builtin_amdgcn_sched_barrier(0);
        unsigned aB = (unsigned)(size_t)(lds_u16*)&As[cur][0];
        unsigned bB = (unsigned)(size_t)(lds_u16*)&Bs[cur][0];
        #pragma unroll
        for (int ks = 0; ks < 2; ++ks) {
            unsigned soff = (unsigned)((((ks * 4) + l4) ^ l7) * 16);
            bf16x8 av[4], bv[2];
            #pragma unroll
            for (int i = 0; i < 4; ++i) av[i] = ldsr(aB + aoff[i] + soff);
            #pragma unroll
            for (int j = 0; j < 2; ++j) bv[j] = ldsr(bB + boff[j] + soff);
            asm volatile("s_waitcnt lgkmcnt(0)" ::: "memory");
            __builtin_amdgcn_sched_barrier(0);
            __builtin_amdgcn_s_setprio(1);
            #pragma unroll
            for (int i = 0; i < 4; ++i)
                #pragma unroll
                for (int j = 0; j < 2; ++j)
                    acc[i][j] = __builtin_amdgcn_mfma_f32_16x16x32_bf16(av[i], bv[j], acc[i][j], 0, 0, 0);
            __builtin_amdgcn_s_setprio(0);
        }
        asm volatile("s_waitcnt vmcnt(0)" ::: "memory");
        __builtin_amdgcn_sched_barrier(0);
        __builtin_amdgcn_s_barrier();
    }

    #pragma unroll
    for (int i = 0; i < 4; ++i) {
        int mrow = m0 + wr*64 + i*16 + l4*4;
        #pragma unroll
        for (int j = 0; j < 2; ++j) {
            int e = e0 + wc*32 + j*16 + l15;
            float bval = bias[e];
            #pragma unroll
            for (int r = 0; r < 4; ++r) {
                int m = mrow + r;
                if (m >= M) continue;
                out[(size_t)m * 1024 + e] = acc[i][j][r] + bval + res[(size_t)m * 1024 + e];
            }
        }
    }
}

// ---------------- fp32 tiled GEMM (final 64-col projection only) ----------------
__global__ __launch_bounds__(256)
void gemm_kernel(const float* __restrict__ A, const float* __restrict__ W,
                 const float* __restrict__ bias, float* __restrict__ C,
                 int M, int K, int E) {
    __shared__ float As[32][64];
    __shared__ float Ws[32][64];
    int tid = threadIdx.x;
    int m0 = blockIdx.x * 64, e0 = blockIdx.y * 64;
    int tx = tid & 15, ty = tid >> 4;
    int lrow = tid >> 2;
    int lkc  = (tid & 3) * 8;
    float acc[4][4] = {};
    const float* Arow = A + (size_t)(m0 + lrow) * K + lkc;
    const float* Wrow = W + (size_t)(e0 + lrow) * K + lkc;
    bool aval = (m0 + lrow) < M;

    for (int k0 = 0; k0 < K; k0 += 32) {
        float4 a0 = make_float4(0.f,0.f,0.f,0.f), a1 = a0;
        if (aval) {
            a0 = *(const float4*)(Arow + k0);
            a1 = *(const float4*)(Arow + k0 + 4);
        }
        float4 w0 = *(const float4*)(Wrow + k0);
        float4 w1 = *(const float4*)(Wrow + k0 + 4);
        As[lkc+0][lrow] = a0.x; As[lkc+1][lrow] = a0.y;
        As[lkc+2][lrow] = a0.z; As[lkc+3][lrow] = a0.w;
        As[lkc+4][lrow] = a1.x; As[lkc+5][lrow] = a1.y;
        As[lkc+6][lrow] = a1.z; As[lkc+7][lrow] = a1.w;
        Ws[lkc+0][lrow] = w0.x; Ws[lkc+1][lrow] = w0.y;
        Ws[lkc+2][lrow] = w0.z; Ws[lkc+3][lrow] = w0.w;
        Ws[lkc+4][lrow] = w1.x; Ws[lkc+5][lrow] = w1.y;
        Ws[lkc+6][lrow] = w1.z; Ws[lkc+7][lrow] = w1.w;
        __syncthreads();
        #pragma unroll
        for (int kk = 0; kk < 32; ++kk) {
            float4 a = *(const float4*)(&As[kk][ty*4]);
            float4 ww = *(const float4*)(&Ws[kk][tx*4]);
            acc[0][0] += a.x*ww.x; acc[0][1] += a.x*ww.y; acc[0][2] += a.x*ww.z; acc[0][3] += a.x*ww.w;
            acc[1][0] += a.y*ww.x; acc[1][1] += a.y*ww.y; acc[1][2] += a.y*ww.z; acc[1][3] += a.y*ww.w;
            acc[2][0] += a.z*ww.x; acc[2][1] += a.z*ww.y; acc[2][2] += a.z*ww.z; acc[2][3] += a.z*ww.w;
            acc[3][0] += a.w*ww.x; acc[3][1] += a.w*ww.y; acc[3][2] += a.w*ww.z; acc[3][3] += a.w*ww.w;
        }
        __syncthreads();
    }
    #pragma unroll
    for (int i = 0; i < 4; ++i) {
        int m = m0 + ty*4 + i;
        if (m >= M) continue;
        #pragma unroll
        for (int j = 0; j < 4; ++j) {
            int e = e0 + tx*4 + j;
            C[(size_t)m * E + e] = acc[i][j] + bias[e];
        }
    }
}

// ---------------- RoPE in place on bf16 [N, H*HD] ----------------
__global__ void ropeb_kernel(unsigned short* __restrict__ x) {
    int idx = blockIdx.x * 256 + threadIdx.x;
    if (idx >= N_ * H_ * 32) return;
    int j = idx & 31;
    int h = (idx >> 5) & (H_ - 1);
    int n = idx >> 9;
    int s = n >> 2;
    float inv = __expf(-(float)j * 0.2878231366242557f);  // ln(10000)/32
    float ang = (float)s * inv;
    float sn, cs;
    __sincosf(ang, &sn, &cs);
    unsigned short* p = x + (size_t)n * D_ + h * HD_ + j;
    float a = b2f(p[0]), c = b2f(p[32]);
    p[0]  = f2b(a * cs - c * sn);
    p[32] = f2b(c * cs + a * sn);
}

// ---------------- V transpose: [s][b][h*64+d] bf16 -> [bh][d][1024] bf16 ----------------
__global__ __launch_bounds__(256)
void vtr_kernel(const unsigned short* __restrict__ vin,
                unsigned short* __restrict__ vout) {
    __shared__ unsigned short T[64][65];
    int tt = blockIdx.x;
    int bh = blockIdx.y;
    int b = bh >> 4, h = bh & 15;
    int tid = threadIdx.x;
    #pragma unroll
    for (int rep = 0; rep < 2; ++rep) {
        int slot = rep * 256 + tid;
        int r = slot >> 3, ch = slot & 7;
        int t = tt * 64 + r;
        unsigned short e[8] = {0,0,0,0,0,0,0,0};
        if (t < S_) {
            const unsigned short* src = vin + ((size_t)t * B_ + b) * D_ + h * HD_ + ch * 8;
            *(ushort4*)&e[0] = *(const ushort4*)(src);
            *(ushort4*)&e[4] = *(const ushort4*)(src + 4);
        }
        #pragma unroll
        for (int u = 0; u < 8; ++u) T[r][ch*8+u] = e[u];
    }
    __syncthreads();
    #pragma unroll
    for (int rep = 0; rep < 2; ++rep) {
        int slot = rep * 256 + tid;
        int d = slot >> 3, ch = slot & 7;
        unsigned short e[8];
        #pragma unroll
        for (int u = 0; u < 8; ++u) e[u] = T[ch*8+u][d];
        unsigned short* dst = vout + ((size_t)bh * 64 + d) * 1024 + tt * 64 + ch * 8;
        *(ushort4*)(dst)     = *(ushort4*)&e[0];
        *(ushort4*)(dst + 4) = *(ushort4*)&e[4];
    }
}

// ---------------- bf16 MFMA flash attention ----------------
__global__ __launch_bounds__(256)
void mattn_kernel(const unsigned short* __restrict__ qg,
                  const unsigned short* __restrict__ kg,
                  const unsigned short* __restrict__ vt,
                  unsigned short* __restrict__ o) {
    __shared__ __align__(16) unsigned short Ks[64 * 64];
    __shared__ __align__(16) unsigned short Vs[64 * 64];
    __shared__ __align__(16) unsigned short Ps[4][16 * 64];

    int bid = blockIdx.x;
    int qt = bid & 15;
    int bh = bid >> 4;
    int b = bh >> 4, h = bh & 15;
    int tid = threadIdx.x;
    int w = tid >> 6, lane = tid & 63;
    int l15 = lane & 15, l4 = lane >> 4, l7 = lane & 7;
    int q0 = qt * 64 + w * 16;

    int srow = lane >> 3;
    int schunk = ((lane & 7) ^ srow) * 8;

    bf16x8 qfr[2];
    {
        int qr = q0 + l15; if (qr > S_ - 1) qr = S_ - 1;
        const unsigned short* qrow = qg + ((size_t)qr * B_ + b) * D_ + h * HD_;
        qfr[0] = *(const bf16x8*)(qrow + l4 * 8);
        qfr[1] = *(const bf16x8*)(qrow + 32 + l4 * 8);
    }

    f32x4 accO[4] = {};
    float mreg[4] = {-1e30f, -1e30f, -1e30f, -1e30f};
    float lreg[4] = {0.f, 0.f, 0.f, 0.f};

    for (int t0 = 0; t0 < 1024; t0 += 64) {
        __syncthreads();
        #pragma unroll
        for (int c = 0; c < 2; ++c) {
            int r0 = w * 16 + c * 8;
            int tr = t0 + r0 + srow; if (tr > S_ - 1) tr = S_ - 1;
            gl16(kg + ((size_t)tr * B_ + b) * D_ + h * HD_ + schunk, &Ks[r0 * 64]);
            gl16(vt + ((size_t)bh * 64 + r0 + srow) * 1024 + t0 + schunk, &Vs[r0 * 64]);
        }
        __syncthreads();

        f32x4 s[4] = {};
        #pragma unroll
        for (int ks = 0; ks < 2; ++ks) {
            int cc = ks * 4 + l4;
            int slot = (cc ^ l7) * 16;
            #pragma unroll
            for (int j = 0; j < 4; ++j) {
                bf16x8 kf = *(const bf16x8*)((const char*)Ks + (j*16 + l15) * 128 + slot);
                s[j] = __builtin_amdgcn_mfma_f32_16x16x32_bf16(qfr[ks], kf, s[j], 0, 0, 0);
            }
        }
        #pragma unroll
        for (int j = 0; j < 4; ++j) {
            int t = t0 + j * 16 + l15;
            if (t >= S_) { s[j][0] = -1e30f; s[j][1] = -1e30f; s[j][2] = -1e30f; s[j][3] = -1e30f; }
        }
        float rm[4], sc[4], rsum[4];
        #pragma unroll
        for (int r = 0; r < 4; ++r)
            rm[r] = fmaxf(fmaxf(s[0][r], s[1][r]), fmaxf(s[2][r], s[3][r]));
        #pragma unroll
        for (int mk = 1; mk <= 8; mk <<= 1) {
            #pragma unroll
            for (int r = 0; r < 4; ++r) rm[r] = fmaxf(rm[r], __shfl_xor(rm[r], mk));
        }
        #pragma unroll
        for (int r = 0; r < 4; ++r) {
            float mn = fmaxf(mreg[r], rm[r]);
            sc[r] = __expf(mreg[r] - mn);
            mreg[r] = mn;
            rsum[r] = 0.f;
        }
        #pragma unroll
        for (int j = 0; j < 4; ++j) {
            int inb = (j * 16 + l15) * 2;
            #pragma unroll
            for (int r = 0; r < 4; ++r) {
                float p = __expf(s[j][r] - mreg[r]);
                rsum[r] += p;
                int row = l4 * 4 + r;
                *(unsigned short*)((char*)&Ps[w][0] + row * 128 +
                    ((((inb >> 4) ^ (row & 7)) << 4)) + (inb & 15)) = f2b(p);
            }
        }
        #pragma unroll
        for (int mk = 1; mk <= 8; mk <<= 1) {
            #pragma unroll
            for (int r = 0; r < 4; ++r) rsum[r] += __shfl_xor(rsum[r], mk);
        }
        #pragma unroll
        for (int r = 0; r < 4; ++r) lreg[r] = lreg[r] * sc[r] + rsum[r];
        #pragma unroll
        for (int j = 0; j < 4; ++j) {
            accO[j][0] *= sc[0]; accO[j][1] *= sc[1];
            accO[j][2] *= sc[2]; accO[j][3] *= sc[3];
        }
        #pragma unroll
        for (int ks = 0; ks < 2; ++ks) {
            int cc = ks * 4 + l4;
            int slot = (cc ^ l7) * 16;
            bf16x8 pf = *(const bf16x8*)((const char*)&Ps[w][0] + l15 * 128 + slot);
            #pragma unroll
            for (int j = 0; j < 4; ++j) {
                bf16x8 vf = *(const bf16x8*)((const char*)Vs + (j*16 + l15) * 128 + slot);
                accO[j] = __builtin_amdgcn_mfma_f32_16x16x32_bf16(pf, vf, accO[j], 0, 0, 0);
            }
        }
    }
    #pragma unroll
    for (int r = 0; r < 4; ++r) {
        int q = q0 + l4 * 4 + r;
        if (q >= S_) continue;
        float inv = 1.0f / lreg[r];
        unsigned short* orow = o + ((size_t)q * B_ + b) * D_ + h * HD_;
        #pragma unroll
        for (int j = 0; j < 4; ++j)
            orow[j * 16 + l15] = f2b(accO[j][r] * inv);
    }
}

extern "C" void kernel_launch(void* const* d_in, const int* in_sizes, int n_in,
                              void* d_out, int out_size, void* d_ws, size_t ws_size,
                              hipStream_t stream) {
    const int*   tokens = (const int*)  d_in[0];
    const float* Wemb   = (const float*)d_in[1];
    const float* Wq     = (const float*)d_in[2];
    const float* bq     = (const float*)d_in[3];
    const float* Wk     = (const float*)d_in[4];
    const float* bk     = (const float*)d_in[5];
    const float* Wv     = (const float*)d_in[6];
    const float* bv     = (const float*)d_in[7];
    const float* Wo     = (const float*)d_in[8];
    const float* bo     = (const float*)d_in[9];
    const float* ln1g   = (const float*)d_in[10];
    const float* ln1b   = (const float*)d_in[11];
    const float* ln2g   = (const float*)d_in[12];
    const float* ln2b   = (const float*)d_in[13];
    const float* W1     = (const float*)d_in[14];
    const float* b1     = (const float*)d_in[15];
    const float* W2     = (const float*)d_in[16];
    const float* b2     = (const float*)d_in[17];
    const float* Wout   = (const float*)d_in[18];
    const float* bout   = (const float*)d_in[19];
    float* out = (float*)d_out;

    const size_t ND = (size_t)N_ * D_;
    const size_t NF = (size_t)N_ * FF_;
    const size_t M1 = (size_t)D_ * D_;
    const size_t M4 = (size_t)FF_ * D_;
    const size_t VT = (size_t)64 * 64 * 1024;

    float* x  = (float*)d_ws;
    unsigned short* hb = (unsigned short*)(x + ND);
    unsigned short* qb = hb + ND;
    unsigned short* kb = qb + ND;
    unsigned short* vb = kb + ND;
    unsigned short* ob = vb + ND;
    unsigned short* vt = ob + ND;
    unsigned short* f1 = vt + VT;
    unsigned short* wb = f1 + NF;           // 12M bf16 per-layer weights

    dim3 blk(256);
    embed_kernel<<<N_, blk, 0, stream>>>(tokens, Wemb, x);

    dim3 gQKV(32, 24);   // 128² tiles: M=4000->32, E=3072->24
    dim3 gW1(32, 32);    // E=4096->32
    dim3 gE64(32, 16);   // 128x64 tiles for E=1024 gemms -> 512 blocks
    dim3 gCv(12288);
    int rth = N_ * H_ * 32;
    dim3 gR((rth + 255) / 256);
    dim3 gVt(16, 64);
    dim3 gAt(16 * 64);
    dim3 gOut((N_ + 63) / 64, 1);

    for (int l = 0; l < L_; ++l) {
        cvtw_kernel<<<gCv, blk, 0, stream>>>(Wq + l*M1, Wk + l*M1, Wv + l*M1,
                                             Wo + l*M1, W1 + l*M4, W2 + l*M4, wb);
        ln_kernel<<<N_, blk, 0, stream>>>(x, ln1g + l*D_, ln1b + l*D_, hb);
        agemm_kernel<0><<<gQKV, blk, 0, stream>>>(hb, wb,
            bq + l*D_, bk + l*D_, bv + l*D_, qb, kb, vb, N_, D_);
        ropeb_kernel<<<gR, blk, 0, stream>>>(qb);
        ropeb_kernel<<<gR, blk, 0, stream>>>(kb);
        vtr_kernel<<<gVt, blk, 0, stream>>>(vb, vt);
        mattn_kernel<<<gAt, blk, 0, stream>>>(qb, kb, vt, ob);
        dgemm_kernel<<<gE64, blk, 0, stream>>>(ob, wb + 3*M1,
            bo + l*D_, x, x, N_, D_);
        ln_kernel<<<N_, blk, 0, stream>>>(x, ln2g + l*D_, ln2b + l*D_, hb);
        agemm_kernel<1><<<gW1, blk, 0, stream>>>(hb, wb + 4*M1,
            b1 + l*FF_, nullptr, nullptr, f1, nullptr, nullptr, N_, D_);
        dgemm_kernel<<<gE64, blk, 0, stream>>>(f1, wb + 4*M1 + M4,
            b2 + l*D_, x, x, N_, FF_);
    }
    gemm_kernel<<<gOut, blk, 0, stream>>>(x, Wout, bout, out, N_, D_, 64);
}

// Round 13
// 1128.278 us; speedup vs baseline: 1.2563x; 1.0534x over previous
//
#include <hip/hip_runtime.h>
#include <hip/hip_bf16.h>
#include <math.h>

#define S_   1000
#define B_   4
#define D_   1024
#define H_   16
#define HD_  64
#define L_   4
#define FF_  4096
#define N_   (S_*B_)   /* 4000 token rows */

typedef __bf16 bf16x8 __attribute__((ext_vector_type(8)));
typedef float  f32x4  __attribute__((ext_vector_type(4)));
typedef __attribute__((address_space(3))) unsigned short lds_u16;

__device__ __forceinline__ unsigned short f2b(float f) {
    unsigned u = __builtin_bit_cast(unsigned, f);
    u = (u + 0x7FFFu + ((u >> 16) & 1u)) >> 16;   // RNE
    return (unsigned short)u;
}
__device__ __forceinline__ float b2f(unsigned short s) {
    unsigned u = (unsigned)s << 16;
    return __builtin_bit_cast(float, u);
}

__device__ __forceinline__ void gl16(const void* g, void* l) {
    __builtin_amdgcn_global_load_lds(
        (const __attribute__((address_space(1))) unsigned int*)g,
        (__attribute__((address_space(3))) unsigned int*)l, 16, 0, 0);
}

// inline-asm LDS read: invisible to compiler's mem-dep model, so it cannot
// auto-insert vmcnt(0) between global_load_lds and this read.
__device__ __forceinline__ bf16x8 ldsr(unsigned addr) {
    bf16x8 r;
    asm volatile("ds_read_b128 %0, %1" : "=v"(r) : "v"(addr));
    return r;
}

// ---------------- embedding lookup ----------------
__global__ void embed_kernel(const int* __restrict__ tokens,
                             const float* __restrict__ emb,
                             float* __restrict__ x) {
    int n = blockIdx.x;
    int tok = tokens[n];
    const float4* src = (const float4*)(emb + (size_t)tok * D_);
    float4* dst = (float4*)(x + (size_t)n * D_);
    dst[threadIdx.x] = src[threadIdx.x];
}

// ---------------- weight fp32->bf16 conversion (one layer, 12M elems) ----------------
__global__ __launch_bounds__(256)
void cvtw_kernel(const float* __restrict__ wq, const float* __restrict__ wk,
                 const float* __restrict__ wv, const float* __restrict__ wo,
                 const float* __restrict__ w1, const float* __restrict__ w2,
                 unsigned short* __restrict__ dst) {
    const size_t M1 = (size_t)D_ * D_;
    const size_t M4 = (size_t)FF_ * D_;
    size_t i = ((size_t)blockIdx.x * 256 + threadIdx.x) * 4;
    const float* src; size_t off;
    if      (i < M1)        { src = wq; off = i; }
    else if (i < 2*M1)      { src = wk; off = i - M1; }
    else if (i < 3*M1)      { src = wv; off = i - 2*M1; }
    else if (i < 4*M1)      { src = wo; off = i - 3*M1; }
    else if (i < 4*M1+M4)   { src = w1; off = i - 4*M1; }
    else                    { src = w2; off = i - 4*M1 - M4; }
    float4 v = *(const float4*)(src + off);
    ushort4 u;
    u.x = f2b(v.x); u.y = f2b(v.y); u.z = f2b(v.z); u.w = f2b(v.w);
    *(ushort4*)(dst + i) = u;
}

// ---------------- layernorm: fp32 in, bf16 out ----------------
__global__ __launch_bounds__(256)
void ln_kernel(const float* __restrict__ in,
               const float* __restrict__ g,
               const float* __restrict__ b,
               unsigned short* __restrict__ out) {
    int n = blockIdx.x;
    int tid = threadIdx.x;
    const float4* row = (const float4*)(in + (size_t)n * D_);
    float4 v = row[tid];
    float s  = v.x + v.y + v.z + v.w;
    float sq = v.x*v.x + v.y*v.y + v.z*v.z + v.w*v.w;
    #pragma unroll
    for (int off = 32; off; off >>= 1) {
        s  += __shfl_down(s, off);
        sq += __shfl_down(sq, off);
    }
    __shared__ float rs[4], rq[4];
    int wid = tid >> 6;
    if ((tid & 63) == 0) { rs[wid] = s; rq[wid] = sq; }
    __syncthreads();
    s  = rs[0] + rs[1] + rs[2] + rs[3];
    sq = rq[0] + rq[1] + rq[2] + rq[3];
    float mean = s * (1.0f / D_);
    float var  = sq * (1.0f / D_) - mean * mean;
    float rstd = rsqrtf(var + 1e-5f);
    float4 gg = ((const float4*)g)[tid];
    float4 bb = ((const float4*)b)[tid];
    ushort4 o;
    o.x = f2b((v.x - mean) * rstd * gg.x + bb.x);
    o.y = f2b((v.y - mean) * rstd * gg.y + bb.y);
    o.z = f2b((v.z - mean) * rstd * gg.z + bb.z);
    o.w = f2b((v.w - mean) * rstd * gg.w + bb.w);
    ((ushort4*)(out + (size_t)n * D_))[tid] = o;
}

// ---------------- 128x64 asm-ds_read 2-phase GEMM, wave tile 32x64 ----------------
// 48 KB LDS dbuf -> 3 blocks/CU (the co-residency lever, confirmed by dgemm).
// 4 waves stacked 4x1 in M; each wave covers ALL 64 e-columns (= one head),
// so the RoPE pair (d, d+32) lives in acc[i][jj] / acc[i][jj+2] of one thread.
// MODE 0: QKV split + fused RoPE on q/k — o0/o1/o2 bf16 stride 1024, q *0.125
// MODE 1: GELU — o0 bf16 stride FF_
template<int MODE>
__global__ __launch_bounds__(256, 2)
void egemm_kernel(const unsigned short* __restrict__ A,
                  const unsigned short* __restrict__ W,
                  const float* __restrict__ bb0, const float* __restrict__ bb1,
                  const float* __restrict__ bb2,
                  unsigned short* __restrict__ o0, unsigned short* __restrict__ o1,
                  unsigned short* __restrict__ o2,
                  int M, int K) {
    __shared__ __align__(16) unsigned short As[2][128 * 64];   // 32 KB
    __shared__ __align__(16) unsigned short Bs[2][64 * 64];    // 16 KB
    int tid = threadIdx.x;
    int w = tid >> 6, lane = tid & 63;
    int m0 = blockIdx.x * 128, e0 = blockIdx.y * 64;
    int l15 = lane & 15, l4 = lane >> 4, l7 = lane & 7;

    f32x4 acc[2][4] = {};

    auto stage = [&](int buf, int kt) {
        #pragma unroll
        for (int rep = 0; rep < 4; ++rep) {
            int slot = rep * 256 + tid;            // A: 128 rows
            int r = slot >> 3, c = slot & 7;
            int ar = m0 + r; if (ar > M - 1) ar = M - 1;
            gl16(A + (size_t)ar * K + kt + (c ^ (r & 7)) * 8, &As[buf][slot * 8]);
        }
        #pragma unroll
        for (int rep = 0; rep < 2; ++rep) {
            int slot = rep * 256 + tid;            // B: 64 rows
            int r = slot >> 3, c = slot & 7;
            gl16(W + (size_t)(e0 + r) * K + kt + (c ^ (r & 7)) * 8, &Bs[buf][slot * 8]);
        }
    };

    int aoff[2], boff[4];
    #pragma unroll
    for (int i = 0; i < 2; ++i) aoff[i] = (w * 32 + i * 16 + l15) * 128;
    #pragma unroll
    for (int j = 0; j < 4; ++j) boff[j] = (j * 16 + l15) * 128;

    stage(0, 0);
    asm volatile("s_waitcnt vmcnt(0)" ::: "memory");
    __builtin_amdgcn_sched_barrier(0);
    __builtin_amdgcn_s_barrier();

    int nk = K >> 6;
    for (int t = 0; t < nk; ++t) {
        int cur = t & 1;
        if (t + 1 < nk) stage(cur ^ 1, (t + 1) << 6);
        __builtin_amdgcn_sched_barrier(0);
        unsigned aB = (unsigned)(size_t)(lds_u16*)&As[cur][0];
        unsigned bB = (unsigned)(size_t)(lds_u16*)&Bs[cur][0];
        #pragma unroll
        for (int ks = 0; ks < 2; ++ks) {
            unsigned soff = (unsigned)((((ks * 4) + l4) ^ l7) * 16);
            bf16x8 av[2], bv[4];
            #pragma unroll
            for (int i = 0; i < 2; ++i) av[i] = ldsr(aB + aoff[i] + soff);
            #pragma unroll
            for (int j = 0; j < 4; ++j) bv[j] = ldsr(bB + boff[j] + soff);
            asm volatile("s_waitcnt lgkmcnt(0)" ::: "memory");
            __builtin_amdgcn_sched_barrier(0);
            __builtin_amdgcn_s_setprio(1);
            #pragma unroll
            for (int i = 0; i < 2; ++i)
                #pragma unroll
                for (int j = 0; j < 4; ++j)
                    acc[i][j] = __builtin_amdgcn_mfma_f32_16x16x32_bf16(av[i], bv[j], acc[i][j], 0, 0, 0);
            __builtin_amdgcn_s_setprio(0);
        }
        asm volatile("s_waitcnt vmcnt(0)" ::: "memory");
        __builtin_amdgcn_sched_barrier(0);
        __builtin_amdgcn_s_barrier();
    }

    // ---- epilogue (C/D: col=lane&15, row=(lane>>4)*4+reg) ----
    if (MODE == 0) {
        int sel = e0 >> 10;                     // 64-tile never crosses 1024 boundary
        int eobase = e0 & 1023;
        const float* bp = (sel == 0) ? bb0 : (sel == 1) ? bb1 : bb2;
        unsigned short* op = (sel == 0) ? o0 : (sel == 1) ? o1 : o2;
        if (sel == 2) {
            #pragma unroll
            for (int i = 0; i < 2; ++i) {
                int mrow = m0 + w*32 + i*16 + l4*4;
                #pragma unroll
                for (int j = 0; j < 4; ++j) {
                    int eo = eobase + j*16 + l15;
                    float bval = bp[eo];
                    #pragma unroll
                    for (int r = 0; r < 4; ++r) {
                        int m = mrow + r;
                        if (m >= M) continue;
                        op[(size_t)m * 1024 + eo] = f2b(acc[i][j][r] + bval);
                    }
                }
            }
        } else {
            // fused RoPE: pair (d, d+32) = acc[i][jj], acc[i][jj+2]; rotate on fp32
            float scale = (sel == 0) ? 0.125f : 1.0f;
            #pragma unroll
            for (int i = 0; i < 2; ++i) {
                int mrow = m0 + w*32 + i*16 + l4*4;
                #pragma unroll
                for (int jj = 0; jj < 2; ++jj) {
                    int d5 = jj*16 + l15;                 // 0..31 within head
                    int eo_a = eobase + d5;
                    int eo_b = eo_a + 32;
                    float ba = bp[eo_a], bbv = bp[eo_b];
                    float invf = __expf(-(float)d5 * 0.2878231366242557f); // ln(1e4)/32
                    #pragma unroll
                    for (int r = 0; r < 4; ++r) {
                        int m = mrow + r;
                        if (m >= M) continue;
                        int s = m >> 2;                   // n = s*B + b, B=4
                        float ang = (float)s * invf;
                        float sn, cs;
                        __sincosf(ang, &sn, &cs);
                        float a = acc[i][jj][r]   + ba;
                        float c = acc[i][jj+2][r] + bbv;
                        op[(size_t)m * 1024 + eo_a] = f2b((a*cs - c*sn) * scale);
                        op[(size_t)m * 1024 + eo_b] = f2b((c*cs + a*sn) * scale);
                    }
                }
            }
        }
    } else {
        #pragma unroll
        for (int i = 0; i < 2; ++i) {
            int mrow = m0 + w*32 + i*16 + l4*4;
            #pragma unroll
            for (int j = 0; j < 4; ++j) {
                int e = e0 + j*16 + l15;
                float bval = bb0[e];
                #pragma unroll
                for (int r = 0; r < 4; ++r) {
                    int m = mrow + r;
                    if (m >= M) continue;
                    float val = acc[i][j][r] + bval;
                    val = 0.5f * val * (1.0f + erff(val * 0.70710678118654752f));
                    o0[(size_t)m * FF_ + e] = f2b(val);
                }
            }
        }
    }
}

// ---------------- 128x64 asm-ds_read 2-phase GEMM for E=1024 (+residual) ----------------
// (round-12 proven) 4 waves 2x2, wave tile 64x32, out fp32 stride 1024, res added.
__global__ __launch_bounds__(256, 2)
void dgemm_kernel(const unsigned short* __restrict__ A,
                  const unsigned short* __restrict__ W,
                  const float* __restrict__ bias,
                  const float* __restrict__ res,
                  float* __restrict__ out,
                  int M, int K) {
    __shared__ __align__(16) unsigned short As[2][128 * 64];   // 32 KB
    __shared__ __align__(16) unsigned short Bs[2][64 * 64];    // 16 KB
    int tid = threadIdx.x;
    int w = tid >> 6, lane = tid & 63;
    int wr = w >> 1, wc = w & 1;
    int m0 = blockIdx.x * 128, e0 = blockIdx.y * 64;
    int l15 = lane & 15, l4 = lane >> 4, l7 = lane & 7;

    f32x4 acc[4][2] = {};

    auto stage = [&](int buf, int kt) {
        #pragma unroll
        for (int rep = 0; rep < 4; ++rep) {
            int slot = rep * 256 + tid;            // A: 128 rows
            int r = slot >> 3, c = slot & 7;
            int ar = m0 + r; if (ar > M - 1) ar = M - 1;
            gl16(A + (size_t)ar * K + kt + (c ^ (r & 7)) * 8, &As[buf][slot * 8]);
        }
        #pragma unroll
        for (int rep = 0; rep < 2; ++rep) {
            int slot = rep * 256 + tid;            // B: 64 rows
            int r = slot >> 3, c = slot & 7;
            gl16(W + (size_t)(e0 + r) * K + kt + (c ^ (r & 7)) * 8, &Bs[buf][slot * 8]);
        }
    };

    int aoff[4], boff[2];
    #pragma unroll
    for (int i = 0; i < 4; ++i) aoff[i] = (wr * 64 + i * 16 + l15) * 128;
    #pragma unroll
    for (int j = 0; j < 2; ++j) boff[j] = (wc * 32 + j * 16 + l15) * 128;

    stage(0, 0);
    asm volatile("s_waitcnt vmcnt(0)" ::: "memory");
    __builtin_amdgcn_sched_barrier(0);
    __builtin_amdgcn_s_barrier();

    int nk = K >> 6;
    for (int t = 0; t < nk; ++t) {
        int cur = t & 1;
        if (t + 1 < nk) stage(cur ^ 1, (t + 1) << 6);
        __builtin_amdgcn_sched_barrier(0);
        unsigned aB = (unsigned)(size_t)(lds_u16*)&As[cur][0];
        unsigned bB = (unsigned)(size_t)(lds_u16*)&Bs[cur][0];
        #pragma unroll
        for (int ks = 0; ks < 2; ++ks) {
            unsigned soff = (unsigned)((((ks * 4) + l4) ^ l7) * 16);
            bf16x8 av[4], bv[2];
            #pragma unroll
            for (int i = 0; i < 4; ++i) av[i] = ldsr(aB + aoff[i] + soff);
            #pragma unroll
            for (int j = 0; j < 2; ++j) bv[j] = ldsr(bB + boff[j] + soff);
            asm volatile("s_waitcnt lgkmcnt(0)" ::: "memory");
            __builtin_amdgcn_sched_barrier(0);
            __builtin_amdgcn_s_setprio(1);
            #pragma unroll
            for (int i = 0; i < 4; ++i)
                #pragma unroll
                for (int j = 0; j < 2; ++j)
                    acc[i][j] = __builtin_amdgcn_mfma_f32_16x16x32_bf16(av[i], bv[j], acc[i][j], 0, 0, 0);
            __builtin_amdgcn_s_setprio(0);
        }
        asm volatile("s_waitcnt vmcnt(0)" ::: "memory");
        __builtin_amdgcn_sched_barrier(0);
        __builtin_amdgcn_s_barrier();
    }

    #pragma unroll
    for (int i = 0; i < 4; ++i) {
        int mrow = m0 + wr*64 + i*16 + l4*4;
        #pragma unroll
        for (int j = 0; j < 2; ++j) {
            int e = e0 + wc*32 + j*16 + l15;
            float bval = bias[e];
            #pragma unroll
            for (int r = 0; r < 4; ++r) {
                int m = mrow + r;
                if (m >= M) continue;
                out[(size_t)m * 1024 + e] = acc[i][j][r] + bval + res[(size_t)m * 1024 + e];
            }
        }
    }
}

// ---------------- fp32 tiled GEMM (final 64-col projection only) ----------------
__global__ __launch_bounds__(256)
void gemm_kernel(const float* __restrict__ A, const float* __restrict__ W,
                 const float* __restrict__ bias, float* __restrict__ C,
                 int M, int K, int E) {
    __shared__ float As[32][64];
    __shared__ float Ws[32][64];
    int tid = threadIdx.x;
    int m0 = blockIdx.x * 64, e0 = blockIdx.y * 64;
    int tx = tid & 15, ty = tid >> 4;
    int lrow = tid >> 2;
    int lkc  = (tid & 3) * 8;
    float acc[4][4] = {};
    const float* Arow = A + (size_t)(m0 + lrow) * K + lkc;
    const float* Wrow = W + (size_t)(e0 + lrow) * K + lkc;
    bool aval = (m0 + lrow) < M;

    for (int k0 = 0; k0 < K; k0 += 32) {
        float4 a0 = make_float4(0.f,0.f,0.f,0.f), a1 = a0;
        if (aval) {
            a0 = *(const float4*)(Arow + k0);
            a1 = *(const float4*)(Arow + k0 + 4);
        }
        float4 w0 = *(const float4*)(Wrow + k0);
        float4 w1 = *(const float4*)(Wrow + k0 + 4);
        As[lkc+0][lrow] = a0.x; As[lkc+1][lrow] = a0.y;
        As[lkc+2][lrow] = a0.z; As[lkc+3][lrow] = a0.w;
        As[lkc+4][lrow] = a1.x; As[lkc+5][lrow] = a1.y;
        As[lkc+6][lrow] = a1.z; As[lkc+7][lrow] = a1.w;
        Ws[lkc+0][lrow] = w0.x; Ws[lkc+1][lrow] = w0.y;
        Ws[lkc+2][lrow] = w0.z; Ws[lkc+3][lrow] = w0.w;
        Ws[lkc+4][lrow] = w1.x; Ws[lkc+5][lrow] = w1.y;
        Ws[lkc+6][lrow] = w1.z; Ws[lkc+7][lrow] = w1.w;
        __syncthreads();
        #pragma unroll
        for (int kk = 0; kk < 32; ++kk) {
            float4 a = *(const float4*)(&As[kk][ty*4]);
            float4 ww = *(const float4*)(&Ws[kk][tx*4]);
            acc[0][0] += a.x*ww.x; acc[0][1] += a.x*ww.y; acc[0][2] += a.x*ww.z; acc[0][3] += a.x*ww.w;
            acc[1][0] += a.y*ww.x; acc[1][1] += a.y*ww.y; acc[1][2] += a.y*ww.z; acc[1][3] += a.y*ww.w;
            acc[2][0] += a.z*ww.x; acc[2][1] += a.z*ww.y; acc[2][2] += a.z*ww.z; acc[2][3] += a.z*ww.w;
            acc[3][0] += a.w*ww.x; acc[3][1] += a.w*ww.y; acc[3][2] += a.w*ww.z; acc[3][3] += a.w*ww.w;
        }
        __syncthreads();
    }
    #pragma unroll
    for (int i = 0; i < 4; ++i) {
        int m = m0 + ty*4 + i;
        if (m >= M) continue;
        #pragma unroll
        for (int j = 0; j < 4; ++j) {
            int e = e0 + tx*4 + j;
            C[(size_t)m * E + e] = acc[i][j] + bias[e];
        }
    }
}

// ---------------- V transpose: [s][b][h*64+d] bf16 -> [bh][d][1024] bf16 ----------------
__global__ __launch_bounds__(256)
void vtr_kernel(const unsigned short* __restrict__ vin,
                unsigned short* __restrict__ vout) {
    __shared__ unsigned short T[64][65];
    int tt = blockIdx.x;
    int bh = blockIdx.y;
    int b = bh >> 4, h = bh & 15;
    int tid = threadIdx.x;
    #pragma unroll
    for (int rep = 0; rep < 2; ++rep) {
        int slot = rep * 256 + tid;
        int r = slot >> 3, ch = slot & 7;
        int t = tt * 64 + r;
        unsigned short e[8] = {0,0,0,0,0,0,0,0};
        if (t < S_) {
            const unsigned short* src = vin + ((size_t)t * B_ + b) * D_ + h * HD_ + ch * 8;
            *(ushort4*)&e[0] = *(const ushort4*)(src);
            *(ushort4*)&e[4] = *(const ushort4*)(src + 4);
        }
        #pragma unroll
        for (int u = 0; u < 8; ++u) T[r][ch*8+u] = e[u];
    }
    __syncthreads();
    #pragma unroll
    for (int rep = 0; rep < 2; ++rep) {
        int slot = rep * 256 + tid;
        int d = slot >> 3, ch = slot & 7;
        unsigned short e[8];
        #pragma unroll
        for (int u = 0; u < 8; ++u) e[u] = T[ch*8+u][d];
        unsigned short* dst = vout + ((size_t)bh * 64 + d) * 1024 + tt * 64 + ch * 8;
        *(ushort4*)(dst)     = *(ushort4*)&e[0];
        *(ushort4*)(dst + 4) = *(ushort4*)&e[4];
    }
}

// ---------------- bf16 MFMA flash attention ----------------
__global__ __launch_bounds__(256)
void mattn_kernel(const unsigned short* __restrict__ qg,
                  const unsigned short* __restrict__ kg,
                  const unsigned short* __restrict__ vt,
                  unsigned short* __restrict__ o) {
    __shared__ __align__(16) unsigned short Ks[64 * 64];
    __shared__ __align__(16) unsigned short Vs[64 * 64];
    __shared__ __align__(16) unsigned short Ps[4][16 * 64];

    int bid = blockIdx.x;
    int qt = bid & 15;
    int bh = bid >> 4;
    int b = bh >> 4, h = bh & 15;
    int tid = threadIdx.x;
    int w = tid >> 6, lane = tid & 63;
    int l15 = lane & 15, l4 = lane >> 4, l7 = lane & 7;
    int q0 = qt * 64 + w * 16;

    int srow = lane >> 3;
    int schunk = ((lane & 7) ^ srow) * 8;

    bf16x8 qfr[2];
    {
        int qr = q0 + l15; if (qr > S_ - 1) qr = S_ - 1;
        const unsigned short* qrow = qg + ((size_t)qr * B_ + b) * D_ + h * HD_;
        qfr[0] = *(const bf16x8*)(qrow + l4 * 8);
        qfr[1] = *(const bf16x8*)(qrow + 32 + l4 * 8);
    }

    f32x4 accO[4] = {};
    float mreg[4] = {-1e30f, -1e30f, -1e30f, -1e30f};
    float lreg[4] = {0.f, 0.f, 0.f, 0.f};

    for (int t0 = 0; t0 < 1024; t0 += 64) {
        __syncthreads();
        #pragma unroll
        for (int c = 0; c < 2; ++c) {
            int r0 = w * 16 + c * 8;
            int tr = t0 + r0 + srow; if (tr > S_ - 1) tr = S_ - 1;
            gl16(kg + ((size_t)tr * B_ + b) * D_ + h * HD_ + schunk, &Ks[r0 * 64]);
            gl16(vt + ((size_t)bh * 64 + r0 + srow) * 1024 + t0 + schunk, &Vs[r0 * 64]);
        }
        __syncthreads();

        f32x4 s[4] = {};
        #pragma unroll
        for (int ks = 0; ks < 2; ++ks) {
            int cc = ks * 4 + l4;
            int slot = (cc ^ l7) * 16;
            #pragma unroll
            for (int j = 0; j < 4; ++j) {
                bf16x8 kf = *(const bf16x8*)((const char*)Ks + (j*16 + l15) * 128 + slot);
                s[j] = __builtin_amdgcn_mfma_f32_16x16x32_bf16(qfr[ks], kf, s[j], 0, 0, 0);
            }
        }
        #pragma unroll
        for (int j = 0; j < 4; ++j) {
            int t = t0 + j * 16 + l15;
            if (t >= S_) { s[j][0] = -1e30f; s[j][1] = -1e30f; s[j][2] = -1e30f; s[j][3] = -1e30f; }
        }
        float rm[4], sc[4], rsum[4];
        #pragma unroll
        for (int r = 0; r < 4; ++r)
            rm[r] = fmaxf(fmaxf(s[0][r], s[1][r]), fmaxf(s[2][r], s[3][r]));
        #pragma unroll
        for (int mk = 1; mk <= 8; mk <<= 1) {
            #pragma unroll
            for (int r = 0; r < 4; ++r) rm[r] = fmaxf(rm[r], __shfl_xor(rm[r], mk));
        }
        #pragma unroll
        for (int r = 0; r < 4; ++r) {
            float mn = fmaxf(mreg[r], rm[r]);
            sc[r] = __expf(mreg[r] - mn);
            mreg[r] = mn;
            rsum[r] = 0.f;
        }
        #pragma unroll
        for (int j = 0; j < 4; ++j) {
            int inb = (j * 16 + l15) * 2;
            #pragma unroll
            for (int r = 0; r < 4; ++r) {
                float p = __expf(s[j][r] - mreg[r]);
                rsum[r] += p;
                int row = l4 * 4 + r;
                *(unsigned short*)((char*)&Ps[w][0] + row * 128 +
                    ((((inb >> 4) ^ (row & 7)) << 4)) + (inb & 15)) = f2b(p);
            }
        }
        #pragma unroll
        for (int mk = 1; mk <= 8; mk <<= 1) {
            #pragma unroll
            for (int r = 0; r < 4; ++r) rsum[r] += __shfl_xor(rsum[r], mk);
        }
        #pragma unroll
        for (int r = 0; r < 4; ++r) lreg[r] = lreg[r] * sc[r] + rsum[r];
        #pragma unroll
        for (int j = 0; j < 4; ++j) {
            accO[j][0] *= sc[0]; accO[j][1] *= sc[1];
            accO[j][2] *= sc[2]; accO[j][3] *= sc[3];
        }
        #pragma unroll
        for (int ks = 0; ks < 2; ++ks) {
            int cc = ks * 4 + l4;
            int slot = (cc ^ l7) * 16;
            bf16x8 pf = *(const bf16x8*)((const char*)&Ps[w][0] + l15 * 128 + slot);
            #pragma unroll
            for (int j = 0; j < 4; ++j) {
                bf16x8 vf = *(const bf16x8*)((const char*)Vs + (j*16 + l15) * 128 + slot);
                accO[j] = __builtin_amdgcn_mfma_f32_16x16x32_bf16(pf, vf, accO[j], 0, 0, 0);
            }
        }
    }
    #pragma unroll
    for (int r = 0; r < 4; ++r) {
        int q = q0 + l4 * 4 + r;
        if (q >= S_) continue;
        float inv = 1.0f / lreg[r];
        unsigned short* orow = o + ((size_t)q * B_ + b) * D_ + h * HD_;
        #pragma unroll
        for (int j = 0; j < 4; ++j)
            orow[j * 16 + l15] = f2b(accO[j][r] * inv);
    }
}

extern "C" void kernel_launch(void* const* d_in, const int* in_sizes, int n_in,
                              void* d_out, int out_size, void* d_ws, size_t ws_size,
                              hipStream_t stream) {
    const int*   tokens = (const int*)  d_in[0];
    const float* Wemb   = (const float*)d_in[1];
    const float* Wq     = (const float*)d_in[2];
    const float* bq     = (const float*)d_in[3];
    const float* Wk     = (const float*)d_in[4];
    const float* bk     = (const float*)d_in[5];
    const float* Wv     = (const float*)d_in[6];
    const float* bv     = (const float*)d_in[7];
    const float* Wo     = (const float*)d_in[8];
    const float* bo     = (const float*)d_in[9];
    const float* ln1g   = (const float*)d_in[10];
    const float* ln1b   = (const float*)d_in[11];
    const float* ln2g   = (const float*)d_in[12];
    const float* ln2b   = (const float*)d_in[13];
    const float* W1     = (const float*)d_in[14];
    const float* b1     = (const float*)d_in[15];
    const float* W2     = (const float*)d_in[16];
    const float* b2     = (const float*)d_in[17];
    const float* Wout   = (const float*)d_in[18];
    const float* bout   = (const float*)d_in[19];
    float* out = (float*)d_out;

    const size_t ND = (size_t)N_ * D_;
    const size_t NF = (size_t)N_ * FF_;
    const size_t M1 = (size_t)D_ * D_;
    const size_t M4 = (size_t)FF_ * D_;
    const size_t VT = (size_t)64 * 64 * 1024;

    float* x  = (float*)d_ws;
    unsigned short* hb = (unsigned short*)(x + ND);
    unsigned short* qb = hb + ND;
    unsigned short* kb = qb + ND;
    unsigned short* vb = kb + ND;
    unsigned short* ob = vb + ND;
    unsigned short* vt = ob + ND;
    unsigned short* f1 = vt + VT;
    unsigned short* wb = f1 + NF;           // 12M bf16 per-layer weights

    dim3 blk(256);
    embed_kernel<<<N_, blk, 0, stream>>>(tokens, Wemb, x);

    dim3 gQKV(32, 48);   // 128x64 tiles: M=4000->32, E=3072->48 (1536 blocks)
    dim3 gW1(32, 64);    // E=4096->64 (2048 blocks)
    dim3 gE64(32, 16);   // E=1024->16 (512 blocks)
    dim3 gCv(12288);
    dim3 gVt(16, 64);
    dim3 gAt(16 * 64);
    dim3 gOut((N_ + 63) / 64, 1);

    for (int l = 0; l < L_; ++l) {
        cvtw_kernel<<<gCv, blk, 0, stream>>>(Wq + l*M1, Wk + l*M1, Wv + l*M1,
                                             Wo + l*M1, W1 + l*M4, W2 + l*M4, wb);
        ln_kernel<<<N_, blk, 0, stream>>>(x, ln1g + l*D_, ln1b + l*D_, hb);
        egemm_kernel<0><<<gQKV, blk, 0, stream>>>(hb, wb,
            bq + l*D_, bk + l*D_, bv + l*D_, qb, kb, vb, N_, D_);
        vtr_kernel<<<gVt, blk, 0, stream>>>(vb, vt);
        mattn_kernel<<<gAt, blk, 0, stream>>>(qb, kb, vt, ob);
        dgemm_kernel<<<gE64, blk, 0, stream>>>(ob, wb + 3*M1,
            bo + l*D_, x, x, N_, D_);
        ln_kernel<<<N_, blk, 0, stream>>>(x, ln2g + l*D_, ln2b + l*D_, hb);
        egemm_kernel<1><<<gW1, blk, 0, stream>>>(hb, wb + 4*M1,
            b1 + l*FF_, nullptr, nullptr, f1, nullptr, nullptr, N_, D_);
        dgemm_kernel<<<gE64, blk, 0, stream>>>(f1, wb + 4*M1 + M4,
            b2 + l*D_, x, x, N_, FF_);
    }
    gemm_kernel<<<gOut, blk, 0, stream>>>(x, Wout, bout, out, N_, D_, 64);
}

// Round 14
// 1091.042 us; speedup vs baseline: 1.2992x; 1.0341x over previous
//
#include <hip/hip_runtime.h>
#include <hip/hip_bf16.h>
#include <math.h>

#define S_   1000
#define B_   4
#define D_   1024
#define H_   16
#define HD_  64
#define L_   4
#define FF_  4096
#define N_   (S_*B_)   /* 4000 token rows */

typedef __bf16 bf16x8 __attribute__((ext_vector_type(8)));
typedef float  f32x4  __attribute__((ext_vector_type(4)));
typedef __attribute__((address_space(3))) unsigned short lds_u16;

__device__ __forceinline__ unsigned short f2b(float f) {
    unsigned u = __builtin_bit_cast(unsigned, f);
    u = (u + 0x7FFFu + ((u >> 16) & 1u)) >> 16;   // RNE
    return (unsigned short)u;
}
__device__ __forceinline__ float b2f(unsigned short s) {
    unsigned u = (unsigned)s << 16;
    return __builtin_bit_cast(float, u);
}

__device__ __forceinline__ void gl16(const void* g, void* l) {
    __builtin_amdgcn_global_load_lds(
        (const __attribute__((address_space(1))) unsigned int*)g,
        (__attribute__((address_space(3))) unsigned int*)l, 16, 0, 0);
}

// inline-asm LDS read: invisible to compiler's mem-dep model, so it cannot
// auto-insert vmcnt(0) between global_load_lds and this read.
__device__ __forceinline__ bf16x8 ldsr(unsigned addr) {
    bf16x8 r;
    asm volatile("ds_read_b128 %0, %1" : "=v"(r) : "v"(addr));
    return r;
}

// ---------------- embedding lookup ----------------
__global__ void embed_kernel(const int* __restrict__ tokens,
                             const float* __restrict__ emb,
                             float* __restrict__ x) {
    int n = blockIdx.x;
    int tok = tokens[n];
    const float4* src = (const float4*)(emb + (size_t)tok * D_);
    float4* dst = (float4*)(x + (size_t)n * D_);
    dst[threadIdx.x] = src[threadIdx.x];
}

// ---------------- weight fp32->bf16 conversion (one layer, 12M elems) ----------------
__global__ __launch_bounds__(256)
void cvtw_kernel(const float* __restrict__ wq, const float* __restrict__ wk,
                 const float* __restrict__ wv, const float* __restrict__ wo,
                 const float* __restrict__ w1, const float* __restrict__ w2,
                 unsigned short* __restrict__ dst) {
    const size_t M1 = (size_t)D_ * D_;
    const size_t M4 = (size_t)FF_ * D_;
    size_t i = ((size_t)blockIdx.x * 256 + threadIdx.x) * 4;
    const float* src; size_t off;
    if      (i < M1)        { src = wq; off = i; }
    else if (i < 2*M1)      { src = wk; off = i - M1; }
    else if (i < 3*M1)      { src = wv; off = i - 2*M1; }
    else if (i < 4*M1)      { src = wo; off = i - 3*M1; }
    else if (i < 4*M1+M4)   { src = w1; off = i - 4*M1; }
    else                    { src = w2; off = i - 4*M1 - M4; }
    float4 v = *(const float4*)(src + off);
    ushort4 u;
    u.x = f2b(v.x); u.y = f2b(v.y); u.z = f2b(v.z); u.w = f2b(v.w);
    *(ushort4*)(dst + i) = u;
}

// ---------------- layernorm: fp32 in, bf16 out ----------------
__global__ __launch_bounds__(256)
void ln_kernel(const float* __restrict__ in,
               const float* __restrict__ g,
               const float* __restrict__ b,
               unsigned short* __restrict__ out) {
    int n = blockIdx.x;
    int tid = threadIdx.x;
    const float4* row = (const float4*)(in + (size_t)n * D_);
    float4 v = row[tid];
    float s  = v.x + v.y + v.z + v.w;
    float sq = v.x*v.x + v.y*v.y + v.z*v.z + v.w*v.w;
    #pragma unroll
    for (int off = 32; off; off >>= 1) {
        s  += __shfl_down(s, off);
        sq += __shfl_down(sq, off);
    }
    __shared__ float rs[4], rq[4];
    int wid = tid >> 6;
    if ((tid & 63) == 0) { rs[wid] = s; rq[wid] = sq; }
    __syncthreads();
    s  = rs[0] + rs[1] + rs[2] + rs[3];
    sq = rq[0] + rq[1] + rq[2] + rq[3];
    float mean = s * (1.0f / D_);
    float var  = sq * (1.0f / D_) - mean * mean;
    float rstd = rsqrtf(var + 1e-5f);
    float4 gg = ((const float4*)g)[tid];
    float4 bb = ((const float4*)b)[tid];
    ushort4 o;
    o.x = f2b((v.x - mean) * rstd * gg.x + bb.x);
    o.y = f2b((v.y - mean) * rstd * gg.y + bb.y);
    o.z = f2b((v.z - mean) * rstd * gg.z + bb.z);
    o.w = f2b((v.w - mean) * rstd * gg.w + bb.w);
    ((ushort4*)(out + (size_t)n * D_))[tid] = o;
}

// ---------------- 256x64 asm-ds_read 2-phase GEMM, 512 thr, wave tile 32x64 ----------------
// Occupancy push: 80 KB LDS dbuf -> 2 blocks/CU x 8 waves = 16 waves/CU (vs
// egemm's 12). Per-wave structure identical to egemm (isolates the TLP knob).
// 8 waves stacked 8x1 in M; each wave covers all 64 e-cols (= one head) so
// the RoPE pair (d, d+32) lives in acc[i][jj] / acc[i][jj+2] of one thread.
// MODE 0: QKV split + fused RoPE — o0/o1/o2 bf16 stride 1024, q *0.125
// MODE 1: GELU — o0 bf16 stride FF_
template<int MODE>
__global__ __launch_bounds__(512, 4)
void ggemm_kernel(const unsigned short* __restrict__ A,
                  const unsigned short* __restrict__ W,
                  const float* __restrict__ bb0, const float* __restrict__ bb1,
                  const float* __restrict__ bb2,
                  unsigned short* __restrict__ o0, unsigned short* __restrict__ o1,
                  unsigned short* __restrict__ o2,
                  int M, int K) {
    __shared__ __align__(16) unsigned short As[2][256 * 64];   // 64 KB
    __shared__ __align__(16) unsigned short Bs[2][64 * 64];    // 16 KB
    int tid = threadIdx.x;
    int w = tid >> 6, lane = tid & 63;
    int m0 = blockIdx.x * 256, e0 = blockIdx.y * 64;
    int l15 = lane & 15, l4 = lane >> 4, l7 = lane & 7;

    f32x4 acc[2][4] = {};

    auto stage = [&](int buf, int kt) {
        #pragma unroll
        for (int rep = 0; rep < 4; ++rep) {
            int slot = rep * 512 + tid;            // A: 256 rows x 8 chunks
            int r = slot >> 3, c = slot & 7;
            int ar = m0 + r; if (ar > M - 1) ar = M - 1;
            gl16(A + (size_t)ar * K + kt + (c ^ (r & 7)) * 8, &As[buf][slot * 8]);
        }
        {
            int slot = tid;                        // B: 64 rows x 8 chunks
            int r = slot >> 3, c = slot & 7;
            gl16(W + (size_t)(e0 + r) * K + kt + (c ^ (r & 7)) * 8, &Bs[buf][slot * 8]);
        }
    };

    int aoff[2], boff[4];
    #pragma unroll
    for (int i = 0; i < 2; ++i) aoff[i] = (w * 32 + i * 16 + l15) * 128;
    #pragma unroll
    for (int j = 0; j < 4; ++j) boff[j] = (j * 16 + l15) * 128;

    stage(0, 0);
    asm volatile("s_waitcnt vmcnt(0)" ::: "memory");
    __builtin_amdgcn_sched_barrier(0);
    __builtin_amdgcn_s_barrier();

    int nk = K >> 6;
    for (int t = 0; t < nk; ++t) {
        int cur = t & 1;
        if (t + 1 < nk) stage(cur ^ 1, (t + 1) << 6);
        __builtin_amdgcn_sched_barrier(0);
        unsigned aB = (unsigned)(size_t)(lds_u16*)&As[cur][0];
        unsigned bB = (unsigned)(size_t)(lds_u16*)&Bs[cur][0];
        #pragma unroll
        for (int ks = 0; ks < 2; ++ks) {
            unsigned soff = (unsigned)((((ks * 4) + l4) ^ l7) * 16);
            bf16x8 av[2], bv[4];
            #pragma unroll
            for (int i = 0; i < 2; ++i) av[i] = ldsr(aB + aoff[i] + soff);
            #pragma unroll
            for (int j = 0; j < 4; ++j) bv[j] = ldsr(bB + boff[j] + soff);
            asm volatile("s_waitcnt lgkmcnt(0)" ::: "memory");
            __builtin_amdgcn_sched_barrier(0);
            __builtin_amdgcn_s_setprio(1);
            #pragma unroll
            for (int i = 0; i < 2; ++i)
                #pragma unroll
                for (int j = 0; j < 4; ++j)
                    acc[i][j] = __builtin_amdgcn_mfma_f32_16x16x32_bf16(av[i], bv[j], acc[i][j], 0, 0, 0);
            __builtin_amdgcn_s_setprio(0);
        }
        asm volatile("s_waitcnt vmcnt(0)" ::: "memory");
        __builtin_amdgcn_sched_barrier(0);
        __builtin_amdgcn_s_barrier();
    }

    // ---- epilogue (C/D: col=lane&15, row=(lane>>4)*4+reg) ----
    if (MODE == 0) {
        int sel = e0 >> 10;                     // 64-tile never crosses 1024 boundary
        int eobase = e0 & 1023;
        const float* bp = (sel == 0) ? bb0 : (sel == 1) ? bb1 : bb2;
        unsigned short* op = (sel == 0) ? o0 : (sel == 1) ? o1 : o2;
        if (sel == 2) {
            #pragma unroll
            for (int i = 0; i < 2; ++i) {
                int mrow = m0 + w*32 + i*16 + l4*4;
                #pragma unroll
                for (int j = 0; j < 4; ++j) {
                    int eo = eobase + j*16 + l15;
                    float bval = bp[eo];
                    #pragma unroll
                    for (int r = 0; r < 4; ++r) {
                        int m = mrow + r;
                        if (m >= M) continue;
                        op[(size_t)m * 1024 + eo] = f2b(acc[i][j][r] + bval);
                    }
                }
            }
        } else {
            // fused RoPE: pair (d, d+32) = acc[i][jj], acc[i][jj+2]; rotate on fp32
            float scale = (sel == 0) ? 0.125f : 1.0f;
            #pragma unroll
            for (int i = 0; i < 2; ++i) {
                int mrow = m0 + w*32 + i*16 + l4*4;
                #pragma unroll
                for (int jj = 0; jj < 2; ++jj) {
                    int d5 = jj*16 + l15;                 // 0..31 within head
                    int eo_a = eobase + d5;
                    int eo_b = eo_a + 32;
                    float ba = bp[eo_a], bbv = bp[eo_b];
                    float invf = __expf(-(float)d5 * 0.2878231366242557f); // ln(1e4)/32
                    #pragma unroll
                    for (int r = 0; r < 4; ++r) {
                        int m = mrow + r;
                        if (m >= M) continue;
                        int s = m >> 2;                   // n = s*B + b, B=4
                        float ang = (float)s * invf;
                        float sn, cs;
                        __sincosf(ang, &sn, &cs);
                        float a = acc[i][jj][r]   + ba;
                        float c = acc[i][jj+2][r] + bbv;
                        op[(size_t)m * 1024 + eo_a] = f2b((a*cs - c*sn) * scale);
                        op[(size_t)m * 1024 + eo_b] = f2b((c*cs + a*sn) * scale);
                    }
                }
            }
        }
    } else {
        #pragma unroll
        for (int i = 0; i < 2; ++i) {
            int mrow = m0 + w*32 + i*16 + l4*4;
            #pragma unroll
            for (int j = 0; j < 4; ++j) {
                int e = e0 + j*16 + l15;
                float bval = bb0[e];
                #pragma unroll
                for (int r = 0; r < 4; ++r) {
                    int m = mrow + r;
                    if (m >= M) continue;
                    float val = acc[i][j][r] + bval;
                    val = 0.5f * val * (1.0f + erff(val * 0.70710678118654752f));
                    o0[(size_t)m * FF_ + e] = f2b(val);
                }
            }
        }
    }
}

// ---------------- 128x64 asm-ds_read 2-phase GEMM for E=1024 (+residual) ----------------
// (round-12 proven) 4 waves 2x2, wave tile 64x32, out fp32 stride 1024, res added.
__global__ __launch_bounds__(256, 2)
void dgemm_kernel(const unsigned short* __restrict__ A,
                  const unsigned short* __restrict__ W,
                  const float* __restrict__ bias,
                  const float* __restrict__ res,
                  float* __restrict__ out,
                  int M, int K) {
    __shared__ __align__(16) unsigned short As[2][128 * 64];   // 32 KB
    __shared__ __align__(16) unsigned short Bs[2][64 * 64];    // 16 KB
    int tid = threadIdx.x;
    int w = tid >> 6, lane = tid & 63;
    int wr = w >> 1, wc = w & 1;
    int m0 = blockIdx.x * 128, e0 = blockIdx.y * 64;
    int l15 = lane & 15, l4 = lane >> 4, l7 = lane & 7;

    f32x4 acc[4][2] = {};

    auto stage = [&](int buf, int kt) {
        #pragma unroll
        for (int rep = 0; rep < 4; ++rep) {
            int slot = rep * 256 + tid;            // A: 128 rows
            int r = slot >> 3, c = slot & 7;
            int ar = m0 + r; if (ar > M - 1) ar = M - 1;
            gl16(A + (size_t)ar * K + kt + (c ^ (r & 7)) * 8, &As[buf][slot * 8]);
        }
        #pragma unroll
        for (int rep = 0; rep < 2; ++rep) {
            int slot = rep * 256 + tid;            // B: 64 rows
            int r = slot >> 3, c = slot & 7;
            gl16(W + (size_t)(e0 + r) * K + kt + (c ^ (r & 7)) * 8, &Bs[buf][slot * 8]);
        }
    };

    int aoff[4], boff[2];
    #pragma unroll
    for (int i = 0; i < 4; ++i) aoff[i] = (wr * 64 + i * 16 + l15) * 128;
    #pragma unroll
    for (int j = 0; j < 2; ++j) boff[j] = (wc * 32 + j * 16 + l15) * 128;

    stage(0, 0);
    asm volatile("s_waitcnt vmcnt(0)" ::: "memory");
    __builtin_amdgcn_sched_barrier(0);
    __builtin_amdgcn_s_barrier();

    int nk = K >> 6;
    for (int t = 0; t < nk; ++t) {
        int cur = t & 1;
        if (t + 1 < nk) stage(cur ^ 1, (t + 1) << 6);
        __builtin_amdgcn_sched_barrier(0);
        unsigned aB = (unsigned)(size_t)(lds_u16*)&As[cur][0];
        unsigned bB = (unsigned)(size_t)(lds_u16*)&Bs[cur][0];
        #pragma unroll
        for (int ks = 0; ks < 2; ++ks) {
            unsigned soff = (unsigned)((((ks * 4) + l4) ^ l7) * 16);
            bf16x8 av[4], bv[2];
            #pragma unroll
            for (int i = 0; i < 4; ++i) av[i] = ldsr(aB + aoff[i] + soff);
            #pragma unroll
            for (int j = 0; j < 2; ++j) bv[j] = ldsr(bB + boff[j] + soff);
            asm volatile("s_waitcnt lgkmcnt(0)" ::: "memory");
            __builtin_amdgcn_sched_barrier(0);
            __builtin_amdgcn_s_setprio(1);
            #pragma unroll
            for (int i = 0; i < 4; ++i)
                #pragma unroll
                for (int j = 0; j < 2; ++j)
                    acc[i][j] = __builtin_amdgcn_mfma_f32_16x16x32_bf16(av[i], bv[j], acc[i][j], 0, 0, 0);
            __builtin_amdgcn_s_setprio(0);
        }
        asm volatile("s_waitcnt vmcnt(0)" ::: "memory");
        __builtin_amdgcn_sched_barrier(0);
        __builtin_amdgcn_s_barrier();
    }

    #pragma unroll
    for (int i = 0; i < 4; ++i) {
        int mrow = m0 + wr*64 + i*16 + l4*4;
        #pragma unroll
        for (int j = 0; j < 2; ++j) {
            int e = e0 + wc*32 + j*16 + l15;
            float bval = bias[e];
            #pragma unroll
            for (int r = 0; r < 4; ++r) {
                int m = mrow + r;
                if (m >= M) continue;
                out[(size_t)m * 1024 + e] = acc[i][j][r] + bval + res[(size_t)m * 1024 + e];
            }
        }
    }
}

// ---------------- fp32 tiled GEMM (final 64-col projection only) ----------------
__global__ __launch_bounds__(256)
void gemm_kernel(const float* __restrict__ A, const float* __restrict__ W,
                 const float* __restrict__ bias, float* __restrict__ C,
                 int M, int K, int E) {
    __shared__ float As[32][64];
    __shared__ float Ws[32][64];
    int tid = threadIdx.x;
    int m0 = blockIdx.x * 64, e0 = blockIdx.y * 64;
    int tx = tid & 15, ty = tid >> 4;
    int lrow = tid >> 2;
    int lkc  = (tid & 3) * 8;
    float acc[4][4] = {};
    const float* Arow = A + (size_t)(m0 + lrow) * K + lkc;
    const float* Wrow = W + (size_t)(e0 + lrow) * K + lkc;
    bool aval = (m0 + lrow) < M;

    for (int k0 = 0; k0 < K; k0 += 32) {
        float4 a0 = make_float4(0.f,0.f,0.f,0.f), a1 = a0;
        if (aval) {
            a0 = *(const float4*)(Arow + k0);
            a1 = *(const float4*)(Arow + k0 + 4);
        }
        float4 w0 = *(const float4*)(Wrow + k0);
        float4 w1 = *(const float4*)(Wrow + k0 + 4);
        As[lkc+0][lrow] = a0.x; As[lkc+1][lrow] = a0.y;
        As[lkc+2][lrow] = a0.z; As[lkc+3][lrow] = a0.w;
        As[lkc+4][lrow] = a1.x; As[lkc+5][lrow] = a1.y;
        As[lkc+6][lrow] = a1.z; As[lkc+7][lrow] = a1.w;
        Ws[lkc+0][lrow] = w0.x; Ws[lkc+1][lrow] = w0.y;
        Ws[lkc+2][lrow] = w0.z; Ws[lkc+3][lrow] = w0.w;
        Ws[lkc+4][lrow] = w1.x; Ws[lkc+5][lrow] = w1.y;
        Ws[lkc+6][lrow] = w1.z; Ws[lkc+7][lrow] = w1.w;
        __syncthreads();
        #pragma unroll
        for (int kk = 0; kk < 32; ++kk) {
            float4 a = *(const float4*)(&As[kk][ty*4]);
            float4 ww = *(const float4*)(&Ws[kk][tx*4]);
            acc[0][0] += a.x*ww.x; acc[0][1] += a.x*ww.y; acc[0][2] += a.x*ww.z; acc[0][3] += a.x*ww.w;
            acc[1][0] += a.y*ww.x; acc[1][1] += a.y*ww.y; acc[1][2] += a.y*ww.z; acc[1][3] += a.y*ww.w;
            acc[2][0] += a.z*ww.x; acc[2][1] += a.z*ww.y; acc[2][2] += a.z*ww.z; acc[2][3] += a.z*ww.w;
            acc[3][0] += a.w*ww.x; acc[3][1] += a.w*ww.y; acc[3][2] += a.w*ww.z; acc[3][3] += a.w*ww.w;
        }
        __syncthreads();
    }
    #pragma unroll
    for (int i = 0; i < 4; ++i) {
        int m = m0 + ty*4 + i;
        if (m >= M) continue;
        #pragma unroll
        for (int j = 0; j < 4; ++j) {
            int e = e0 + tx*4 + j;
            C[(size_t)m * E + e] = acc[i][j] + bias[e];
        }
    }
}

// ---------------- V transpose: [s][b][h*64+d] bf16 -> [bh][d][1024] bf16 ----------------
__global__ __launch_bounds__(256)
void vtr_kernel(const unsigned short* __restrict__ vin,
                unsigned short* __restrict__ vout) {
    __shared__ unsigned short T[64][65];
    int tt = blockIdx.x;
    int bh = blockIdx.y;
    int b = bh >> 4, h = bh & 15;
    int tid = threadIdx.x;
    #pragma unroll
    for (int rep = 0; rep < 2; ++rep) {
        int slot = rep * 256 + tid;
        int r = slot >> 3, ch = slot & 7;
        int t = tt * 64 + r;
        unsigned short e[8] = {0,0,0,0,0,0,0,0};
        if (t < S_) {
            const unsigned short* src = vin + ((size_t)t * B_ + b) * D_ + h * HD_ + ch * 8;
            *(ushort4*)&e[0] = *(const ushort4*)(src);
            *(ushort4*)&e[4] = *(const ushort4*)(src + 4);
        }
        #pragma unroll
        for (int u = 0; u < 8; ++u) T[r][ch*8+u] = e[u];
    }
    __syncthreads();
    #pragma unroll
    for (int rep = 0; rep < 2; ++rep) {
        int slot = rep * 256 + tid;
        int d = slot >> 3, ch = slot & 7;
        unsigned short e[8];
        #pragma unroll
        for (int u = 0; u < 8; ++u) e[u] = T[ch*8+u][d];
        unsigned short* dst = vout + ((size_t)bh * 64 + d) * 1024 + tt * 64 + ch * 8;
        *(ushort4*)(dst)     = *(ushort4*)&e[0];
        *(ushort4*)(dst + 4) = *(ushort4*)&e[4];
    }
}

// ---------------- bf16 MFMA flash attention ----------------
__global__ __launch_bounds__(256)
void mattn_kernel(const unsigned short* __restrict__ qg,
                  const unsigned short* __restrict__ kg,
                  const unsigned short* __restrict__ vt,
                  unsigned short* __restrict__ o) {
    __shared__ __align__(16) unsigned short Ks[64 * 64];
    __shared__ __align__(16) unsigned short Vs[64 * 64];
    __shared__ __align__(16) unsigned short Ps[4][16 * 64];

    int bid = blockIdx.x;
    int qt = bid & 15;
    int bh = bid >> 4;
    int b = bh >> 4, h = bh & 15;
    int tid = threadIdx.x;
    int w = tid >> 6, lane = tid & 63;
    int l15 = lane & 15, l4 = lane >> 4, l7 = lane & 7;
    int q0 = qt * 64 + w * 16;

    int srow = lane >> 3;
    int schunk = ((lane & 7) ^ srow) * 8;

    bf16x8 qfr[2];
    {
        int qr = q0 + l15; if (qr > S_ - 1) qr = S_ - 1;
        const unsigned short* qrow = qg + ((size_t)qr * B_ + b) * D_ + h * HD_;
        qfr[0] = *(const bf16x8*)(qrow + l4 * 8);
        qfr[1] = *(const bf16x8*)(qrow + 32 + l4 * 8);
    }

    f32x4 accO[4] = {};
    float mreg[4] = {-1e30f, -1e30f, -1e30f, -1e30f};
    float lreg[4] = {0.f, 0.f, 0.f, 0.f};

    for (int t0 = 0; t0 < 1024; t0 += 64) {
        __syncthreads();
        #pragma unroll
        for (int c = 0; c < 2; ++c) {
            int r0 = w * 16 + c * 8;
            int tr = t0 + r0 + srow; if (tr > S_ - 1) tr = S_ - 1;
            gl16(kg + ((size_t)tr * B_ + b) * D_ + h * HD_ + schunk, &Ks[r0 * 64]);
            gl16(vt + ((size_t)bh * 64 + r0 + srow) * 1024 + t0 + schunk, &Vs[r0 * 64]);
        }
        __syncthreads();

        f32x4 s[4] = {};
        #pragma unroll
        for (int ks = 0; ks < 2; ++ks) {
            int cc = ks * 4 + l4;
            int slot = (cc ^ l7) * 16;
            #pragma unroll
            for (int j = 0; j < 4; ++j) {
                bf16x8 kf = *(const bf16x8*)((const char*)Ks + (j*16 + l15) * 128 + slot);
                s[j] = __builtin_amdgcn_mfma_f32_16x16x32_bf16(qfr[ks], kf, s[j], 0, 0, 0);
            }
        }
        #pragma unroll
        for (int j = 0; j < 4; ++j) {
            int t = t0 + j * 16 + l15;
            if (t >= S_) { s[j][0] = -1e30f; s[j][1] = -1e30f; s[j][2] = -1e30f; s[j][3] = -1e30f; }
        }
        float rm[4], sc[4], rsum[4];
        #pragma unroll
        for (int r = 0; r < 4; ++r)
            rm[r] = fmaxf(fmaxf(s[0][r], s[1][r]), fmaxf(s[2][r], s[3][r]));
        #pragma unroll
        for (int mk = 1; mk <= 8; mk <<= 1) {
            #pragma unroll
            for (int r = 0; r < 4; ++r) rm[r] = fmaxf(rm[r], __shfl_xor(rm[r], mk));
        }
        #pragma unroll
        for (int r = 0; r < 4; ++r) {
            float mn = fmaxf(mreg[r], rm[r]);
            sc[r] = __expf(mreg[r] - mn);
            mreg[r] = mn;
            rsum[r] = 0.f;
        }
        #pragma unroll
        for (int j = 0; j < 4; ++j) {
            int inb = (j * 16 + l15) * 2;
            #pragma unroll
            for (int r = 0; r < 4; ++r) {
                float p = __expf(s[j][r] - mreg[r]);
                rsum[r] += p;
                int row = l4 * 4 + r;
                *(unsigned short*)((char*)&Ps[w][0] + row * 128 +
                    ((((inb >> 4) ^ (row & 7)) << 4)) + (inb & 15)) = f2b(p);
            }
        }
        #pragma unroll
        for (int mk = 1; mk <= 8; mk <<= 1) {
            #pragma unroll
            for (int r = 0; r < 4; ++r) rsum[r] += __shfl_xor(rsum[r], mk);
        }
        #pragma unroll
        for (int r = 0; r < 4; ++r) lreg[r] = lreg[r] * sc[r] + rsum[r];
        #pragma unroll
        for (int j = 0; j < 4; ++j) {
            accO[j][0] *= sc[0]; accO[j][1] *= sc[1];
            accO[j][2] *= sc[2]; accO[j][3] *= sc[3];
        }
        #pragma unroll
        for (int ks = 0; ks < 2; ++ks) {
            int cc = ks * 4 + l4;
            int slot = (cc ^ l7) * 16;
            bf16x8 pf = *(const bf16x8*)((const char*)&Ps[w][0] + l15 * 128 + slot);
            #pragma unroll
            for (int j = 0; j < 4; ++j) {
                bf16x8 vf = *(const bf16x8*)((const char*)Vs + (j*16 + l15) * 128 + slot);
                accO[j] = __builtin_amdgcn_mfma_f32_16x16x32_bf16(pf, vf, accO[j], 0, 0, 0);
            }
        }
    }
    #pragma unroll
    for (int r = 0; r < 4; ++r) {
        int q = q0 + l4 * 4 + r;
        if (q >= S_) continue;
        float inv = 1.0f / lreg[r];
        unsigned short* orow = o + ((size_t)q * B_ + b) * D_ + h * HD_;
        #pragma unroll
        for (int j = 0; j < 4; ++j)
            orow[j * 16 + l15] = f2b(accO[j][r] * inv);
    }
}

extern "C" void kernel_launch(void* const* d_in, const int* in_sizes, int n_in,
                              void* d_out, int out_size, void* d_ws, size_t ws_size,
                              hipStream_t stream) {
    const int*   tokens = (const int*)  d_in[0];
    const float* Wemb   = (const float*)d_in[1];
    const float* Wq     = (const float*)d_in[2];
    const float* bq     = (const float*)d_in[3];
    const float* Wk     = (const float*)d_in[4];
    const float* bk     = (const float*)d_in[5];
    const float* Wv     = (const float*)d_in[6];
    const float* bv     = (const float*)d_in[7];
    const float* Wo     = (const float*)d_in[8];
    const float* bo     = (const float*)d_in[9];
    const float* ln1g   = (const float*)d_in[10];
    const float* ln1b   = (const float*)d_in[11];
    const float* ln2g   = (const float*)d_in[12];
    const float* ln2b   = (const float*)d_in[13];
    const float* W1     = (const float*)d_in[14];
    const float* b1     = (const float*)d_in[15];
    const float* W2     = (const float*)d_in[16];
    const float* b2     = (const float*)d_in[17];
    const float* Wout   = (const float*)d_in[18];
    const float* bout   = (const float*)d_in[19];
    float* out = (float*)d_out;

    const size_t ND = (size_t)N_ * D_;
    const size_t NF = (size_t)N_ * FF_;
    const size_t M1 = (size_t)D_ * D_;
    const size_t M4 = (size_t)FF_ * D_;
    const size_t VT = (size_t)64 * 64 * 1024;

    float* x  = (float*)d_ws;
    unsigned short* hb = (unsigned short*)(x + ND);
    unsigned short* qb = hb + ND;
    unsigned short* kb = qb + ND;
    unsigned short* vb = kb + ND;
    unsigned short* ob = vb + ND;
    unsigned short* vt = ob + ND;
    unsigned short* f1 = vt + VT;
    unsigned short* wb = f1 + NF;           // 12M bf16 per-layer weights

    dim3 blk(256);
    embed_kernel<<<N_, blk, 0, stream>>>(tokens, Wemb, x);

    dim3 gQKV(16, 48);   // 256x64 tiles: M=4000->16, E=3072->48 (768 blocks)
    dim3 gW1(16, 64);    // E=4096->64 (1024 blocks)
    dim3 gE64(32, 16);   // 128x64 tiles, E=1024->16 (512 blocks)
    dim3 gCv(12288);
    dim3 gVt(16, 64);
    dim3 gAt(16 * 64);
    dim3 gOut((N_ + 63) / 64, 1);

    for (int l = 0; l < L_; ++l) {
        cvtw_kernel<<<gCv, blk, 0, stream>>>(Wq + l*M1, Wk + l*M1, Wv + l*M1,
                                             Wo + l*M1, W1 + l*M4, W2 + l*M4, wb);
        ln_kernel<<<N_, blk, 0, stream>>>(x, ln1g + l*D_, ln1b + l*D_, hb);
        ggemm_kernel<0><<<gQKV, dim3(512), 0, stream>>>(hb, wb,
            bq + l*D_, bk + l*D_, bv + l*D_, qb, kb, vb, N_, D_);
        vtr_kernel<<<gVt, blk, 0, stream>>>(vb, vt);
        mattn_kernel<<<gAt, blk, 0, stream>>>(qb, kb, vt, ob);
        dgemm_kernel<<<gE64, blk, 0, stream>>>(ob, wb + 3*M1,
            bo + l*D_, x, x, N_, D_);
        ln_kernel<<<N_, blk, 0, stream>>>(x, ln2g + l*D_, ln2b + l*D_, hb);
        ggemm_kernel<1><<<gW1, dim3(512), 0, stream>>>(hb, wb + 4*M1,
            b1 + l*FF_, nullptr, nullptr, f1, nullptr, nullptr, N_, D_);
        dgemm_kernel<<<gE64, blk, 0, stream>>>(f1, wb + 4*M1 + M4,
            b2 + l*D_, x, x, N_, FF_);
    }
    gemm_kernel<<<gOut, blk, 0, stream>>>(x, Wout, bout, out, N_, D_, 64);
}